// Round 1
// 1471.094 us; speedup vs baseline: 1.1708x; 1.1708x over previous
//
#include <hip/hip_runtime.h>
#include <hip/hip_bf16.h>

#define N_USERS 100000
#define N_ITEMS 50000
#define N_NODES 150000
#define DD 64
#define FF 768
#define N_EDGES_C 4800000
#define BATCH 4096
#define LN_EPS 1e-5f
#define CONTENT_LOSS_W 0.1f

#define SCAN_BLK 1024
#define SCAN_NBLK 147   // ceil(150000/1024)

#define NBUCK 147       // ceil(150000/1024) - 1024-node buckets
#define BIN_TILE 4096

__device__ inline float b2f(unsigned short v) {
    union { unsigned int i; float f; } u;
    u.i = ((unsigned int)v) << 16;
    return u.f;
}
__device__ inline unsigned short f2b(float f) {
    union { float f; unsigned int i; } u; u.f = f;
    unsigned int r = u.i + 0x7fff + ((u.i >> 16) & 1);   // RNE
    return (unsigned short)(r >> 16);
}

// ---------------------------------------------------------------------------
// K1: user emb init f32 -> bf16
// ---------------------------------------------------------------------------
__global__ __launch_bounds__(256) void init_users_k(
    const float* __restrict__ ue, unsigned short* __restrict__ emb)
{
    int gid = blockIdx.x * 256 + threadIdx.x;   // N_USERS*DD/4 threads
    size_t base = (size_t)gid * 4;
    float4 v = *reinterpret_cast<const float4*>(ue + base);
    ushort4 o;
    o.x = f2b(v.x); o.y = f2b(v.y); o.z = f2b(v.z); o.w = f2b(v.w);
    *reinterpret_cast<ushort4*>(emb + base) = o;
}

// ---------------------------------------------------------------------------
// K2: content projection + gate + combine
// ---------------------------------------------------------------------------
__global__ __launch_bounds__(256) void content_combine_k(
    const float* __restrict__ cf, const float* __restrict__ Wp,
    const float* __restrict__ bp, const float* __restrict__ wg,
    const float* __restrict__ bg, const float* __restrict__ item_emb,
    float* __restrict__ items_content,
    unsigned short* __restrict__ emb, float* __restrict__ acc_items)
{
    __shared__ float cf_s[16][FF];           // 48 KB
    const int tid = threadIdx.x;
    const int row0 = blockIdx.x * 16;

    {
        const int lrow = tid >> 4;
        const int sub  = tid & 15;
        const float* src = cf + (size_t)(row0 + lrow) * FF;
        #pragma unroll
        for (int i = 0; i < 12; ++i) {
            int k = sub * 4 + i * 64;
            float4 u = *reinterpret_cast<const float4*>(src + k);
            *reinterpret_cast<float4*>(&cf_s[lrow][k]) = u;
        }
    }
    __syncthreads();

    const int lane = tid & 63;
    const int rg   = tid >> 6;
    const int rbase = rg * 4;

    float g[4];
    const float bgv = bg[0];
    #pragma unroll
    for (int r = 0; r < 4; ++r) {
        float gp = 0.f;
        for (int k = lane; k < FF; k += 64)
            gp += cf_s[rbase + r][k] * wg[k];
        #pragma unroll
        for (int off = 32; off; off >>= 1) gp += __shfl_xor(gp, off);
        g[r] = 1.f / (1.f + __expf(-(gp + bgv)));
    }

    float a0 = 0.f, a1 = 0.f, a2 = 0.f, a3 = 0.f;
    #pragma unroll 4
    for (int k = 0; k < FF; ++k) {
        float wv = Wp[k * DD + lane];
        a0 += cf_s[rbase + 0][k] * wv;
        a1 += cf_s[rbase + 1][k] * wv;
        a2 += cf_s[rbase + 2][k] * wv;
        a3 += cf_s[rbase + 3][k] * wv;
    }

    const float bpv = bp[lane];
    float av[4] = {a0, a1, a2, a3};
    #pragma unroll
    for (int r = 0; r < 4; ++r) {
        int row = row0 + rbase + r;
        float ic = av[r] + bpv;
        float gr = g[r];
        float it = (1.f - gr) * item_emb[(size_t)row * DD + lane] + gr * ic;
        items_content[(size_t)row * DD + lane] = ic;
        emb[(size_t)(N_USERS + row) * DD + lane] = f2b(it);
        acc_items[(size_t)row * DD + lane] = it;
    }
}

// ---------------------------------------------------------------------------
// CSR build: histogram -> scan -> binning (2-phase, write-combined)
// ---------------------------------------------------------------------------
__global__ __launch_bounds__(256) void hist_k(
    const int* __restrict__ ed, int* __restrict__ cursor)
{
    int t = blockIdx.x * 256 + threadIdx.x;
    if (t < N_EDGES_C / 4) {
        int4 d = reinterpret_cast<const int4*>(ed)[t];
        atomicAdd(&cursor[d.x], 1);
        atomicAdd(&cursor[d.y], 1);
        atomicAdd(&cursor[d.z], 1);
        atomicAdd(&cursor[d.w], 1);
    }
}

__global__ __launch_bounds__(SCAN_BLK) void scan_blocksum_k(
    const int* __restrict__ cursor, int* __restrict__ partials)
{
    __shared__ int sdata[SCAN_BLK];
    int i = blockIdx.x * SCAN_BLK + threadIdx.x;
    int v = (i < N_NODES) ? cursor[i] : 0;
    sdata[threadIdx.x] = v;
    __syncthreads();
    for (int off = SCAN_BLK / 2; off; off >>= 1) {
        if (threadIdx.x < off) sdata[threadIdx.x] += sdata[threadIdx.x + off];
        __syncthreads();
    }
    if (threadIdx.x == 0) partials[blockIdx.x] = sdata[0];
}

__global__ __launch_bounds__(256) void scan_partials_k(int* __restrict__ partials)
{
    __shared__ int sdata[256];
    int t = threadIdx.x;
    int v = (t < SCAN_NBLK) ? partials[t] : 0;
    sdata[t] = v;
    __syncthreads();
    for (int off = 1; off < 256; off <<= 1) {
        int x = (t >= off) ? sdata[t - off] : 0;
        __syncthreads();
        sdata[t] += x;
        __syncthreads();
    }
    if (t < SCAN_NBLK) partials[t] = sdata[t] - v;   // exclusive
}

__global__ __launch_bounds__(SCAN_BLK) void scan_write_k(
    const int* __restrict__ partials, int* __restrict__ cursor)
{
    __shared__ int sdata[SCAN_BLK];
    int i = blockIdx.x * SCAN_BLK + threadIdx.x;
    int t = threadIdx.x;
    int v = (i < N_NODES) ? cursor[i] : 0;
    sdata[t] = v;
    __syncthreads();
    for (int off = 1; off < SCAN_BLK; off <<= 1) {
        int x = (t >= off) ? sdata[t - off] : 0;
        __syncthreads();
        sdata[t] += x;
        __syncthreads();
    }
    if (i < N_NODES)
        cursor[i] = partials[blockIdx.x] + sdata[t] - v;   // exclusive start
}

// bucket_cursor[b] = start offset of bucket b (= cursor at 1024-node bounds)
__global__ __launch_bounds__(256) void bucket_init_k(
    const int* __restrict__ cursor, int* __restrict__ bucket_cursor)
{
    int t = threadIdx.x;
    if (t < NBUCK) bucket_cursor[t] = cursor[t << 10];
}

// Pass A: tile-sort edges into 147 coarse buckets with LDS write combining.
// binned entry: x = (src<<10)|(dst&1023), y = weight bits
__global__ __launch_bounds__(256) void bin_k(
    const int* __restrict__ ed, const int* __restrict__ es,
    const float* __restrict__ ew, int* __restrict__ bucket_cursor,
    uint2* __restrict__ binned)
{
    __shared__ uint2 stage[BIN_TILE];        // 32 KB
    __shared__ int h[NBUCK];                 // hist, then running cursor
    __shared__ int o[NBUCK];                 // exclusive offsets
    __shared__ int gbase[NBUCK];
    __shared__ int scanbuf[256];

    const int t = threadIdx.x;
    const int base = blockIdx.x * BIN_TILE;
    const int cnt = min(BIN_TILE, N_EDGES_C - base);

    for (int i = t; i < NBUCK; i += 256) h[i] = 0;
    __syncthreads();

    int ld[16]; int ls[16]; float lw[16]; int lb[16];
    #pragma unroll
    for (int k = 0; k < 16; ++k) {
        int i = t + k * 256;
        if (i < cnt) {
            int d = ed[base + i];
            ld[k] = d;
            ls[k] = es[base + i];
            lw[k] = ew[base + i];
            int b = d >> 10;
            lb[k] = b;
            atomicAdd(&h[b], 1);
        } else lb[k] = -1;
    }
    __syncthreads();

    // exclusive scan of h -> o (NBUCK <= 256)
    {
        int v = (t < NBUCK) ? h[t] : 0;
        scanbuf[t] = v;
        __syncthreads();
        for (int off = 1; off < 256; off <<= 1) {
            int x = (t >= off) ? scanbuf[t - off] : 0;
            __syncthreads();
            scanbuf[t] += x;
            __syncthreads();
        }
        if (t < NBUCK) o[t] = scanbuf[t] - v;
    }
    __syncthreads();

    if (t < NBUCK) h[t] = o[t];   // running cursors
    __syncthreads();

    #pragma unroll
    for (int k = 0; k < 16; ++k) {
        if (lb[k] >= 0) {
            int p = atomicAdd(&h[lb[k]], 1);
            unsigned key = ((unsigned)ls[k] << 10) | (unsigned)(ld[k] & 1023);
            stage[p] = make_uint2(key, __float_as_uint(lw[k]));
        }
    }
    __syncthreads();

    // reserve contiguous global space per bucket (h now = end offsets)
    if (t < NBUCK) {
        int c = h[t] - o[t];
        gbase[t] = (c > 0) ? atomicAdd(&bucket_cursor[t], c) : 0;
    }
    __syncthreads();

    // copy out, coalesced within bucket segments
    for (int i = t; i < cnt; i += 256) {
        int lo = 0, hi = NBUCK - 1;          // largest b with o[b] <= i
        while (lo < hi) {
            int mid = (lo + hi + 1) >> 1;
            if (o[mid] <= i) lo = mid; else hi = mid - 1;
        }
        binned[gbase[lo] + (i - o[lo])] = stage[i];
    }
}

// Pass B: one block owns one 1024-node bucket; scatter to final CSR slots.
// All writes land in one 261KB region owned by this block -> L2 combining.
__global__ __launch_bounds__(256) void scatter_k(
    const uint2* __restrict__ binned, const int* __restrict__ cursor,
    uint2* __restrict__ adj)
{
    __shared__ int lc[1024];
    const int b = blockIdx.x;
    const int t = threadIdx.x;
    const int nb = b << 10;
    for (int j = t; j < 1024; j += 256) {
        int n = nb + j;
        lc[j] = (n < N_NODES) ? cursor[n] : 0;
    }
    __syncthreads();
    const int s0 = cursor[nb];
    const int s1 = (b == NBUCK - 1) ? N_EDGES_C : cursor[nb + 1024];
    for (int i = s0 + t; i < s1; i += 256) {
        uint2 e = binned[i];
        int ln = (int)(e.x & 1023u);
        unsigned src = e.x >> 10;
        int p = atomicAdd(&lc[ln], 1);
        adj[p] = make_uint2(src, e.y);
    }
}

// ---------------------------------------------------------------------------
// K3: fused aggregate + layernorm + residual (bf16 emb state)
// cursor holds exclusive START offsets (unchanged by build).
// ---------------------------------------------------------------------------
__global__ __launch_bounds__(256) void agg_ln_k(
    const unsigned short* __restrict__ emb_in,
    unsigned short* __restrict__ emb_out,
    float* __restrict__ acc_items,
    const int* __restrict__ cursor, const uint2* __restrict__ adj)
{
    int n = blockIdx.x * 4 + (threadIdx.x >> 6);   // 37500 blocks exact
    int lane = threadIdx.x & 63;
    int beg = cursor[n];
    int end = (n == N_NODES - 1) ? N_EDGES_C : cursor[n + 1];

    float a = 0.f;
    int j = beg;
    for (; j + 3 < end; j += 4) {
        uint2 e0 = adj[j], e1 = adj[j + 1], e2 = adj[j + 2], e3 = adj[j + 3];
        float v0 = b2f(emb_in[(size_t)e0.x * DD + lane]);
        float v1 = b2f(emb_in[(size_t)e1.x * DD + lane]);
        float v2 = b2f(emb_in[(size_t)e2.x * DD + lane]);
        float v3 = b2f(emb_in[(size_t)e3.x * DD + lane]);
        a += __uint_as_float(e0.y) * v0;
        a += __uint_as_float(e1.y) * v1;
        a += __uint_as_float(e2.y) * v2;
        a += __uint_as_float(e3.y) * v3;
    }
    for (; j < end; ++j) {
        uint2 e0 = adj[j];
        a += __uint_as_float(e0.y) * b2f(emb_in[(size_t)e0.x * DD + lane]);
    }

    float s = a;
    #pragma unroll
    for (int off = 32; off; off >>= 1) s += __shfl_xor(s, off);
    float m = s * (1.f / 64.f);
    float dlt = a - m;
    float vv = dlt * dlt;
    #pragma unroll
    for (int off = 32; off; off >>= 1) vv += __shfl_xor(vv, off);
    float var = vv * (1.f / 64.f);
    float y = dlt * rsqrtf(var + LN_EPS);

    size_t o = (size_t)n * DD + lane;
    float e_new = y + b2f(emb_in[o]);
    emb_out[o] = f2b(e_new);
    if (n >= N_USERS)
        acc_items[(size_t)(n - N_USERS) * DD + lane] += e_new;
}

// ---------------------------------------------------------------------------
// K4: accumulate sampled rows directly into out
// ---------------------------------------------------------------------------
__global__ __launch_bounds__(256) void gather_acc_k(
    const int* __restrict__ users, const int* __restrict__ pos,
    const int* __restrict__ neg, const unsigned short* __restrict__ emb_state,
    float* __restrict__ out, int init)
{
    int gid = blockIdx.x * 256 + threadIdx.x;   // 3*BATCH*DD = 786432
    int part = gid / (BATCH * DD);
    int r = gid - part * (BATCH * DD);
    int b = r >> 6, c = r & 63;
    int node;
    if (part == 0)      node = users[b];
    else if (part == 1) node = N_USERS + pos[b];
    else                node = N_USERS + neg[b];
    float v = b2f(emb_state[(size_t)node * DD + c]);
    if (init) out[gid] = v;
    else      out[gid] += v;
}

// ---------------------------------------------------------------------------
// K5: content loss
// ---------------------------------------------------------------------------
__global__ __launch_bounds__(256) void loss_k(
    const float* __restrict__ acc_items, const float* __restrict__ ic,
    float* __restrict__ loss_slot)
{
    const int total = N_ITEMS * DD;
    int stride = gridDim.x * 256;
    float p = 0.f;
    for (int i = blockIdx.x * 256 + threadIdx.x; i < total; i += stride) {
        float d = acc_items[i] * 0.25f - ic[i];
        p += d * d;
    }
    #pragma unroll
    for (int off = 32; off; off >>= 1) p += __shfl_xor(p, off);
    __shared__ float red[4];
    if ((threadIdx.x & 63) == 0) red[threadIdx.x >> 6] = p;
    __syncthreads();
    if (threadIdx.x == 0)
        atomicAdd(loss_slot, red[0] + red[1] + red[2] + red[3]);
}

// ---------------------------------------------------------------------------
// K6: out *= 0.25 ; write loss element
// ---------------------------------------------------------------------------
__global__ __launch_bounds__(256) void final_out_k(
    const float* __restrict__ loss_slot, float* __restrict__ out)
{
    int gid = blockIdx.x * 256 + threadIdx.x;
    out[gid] *= 0.25f;
    if (gid == 0)
        out[3 * BATCH * DD] =
            loss_slot[0] * (CONTENT_LOSS_W / (float)(N_ITEMS * DD));
}

// ---------------------------------------------------------------------------
extern "C" void kernel_launch(void* const* d_in, const int* in_sizes, int n_in,
                              void* d_out, int out_size, void* d_ws, size_t ws_size,
                              hipStream_t stream)
{
    const int* users = (const int*)d_in[0];
    const int* pos   = (const int*)d_in[1];
    const int* neg   = (const int*)d_in[2];
    const int* es    = (const int*)d_in[3];
    const int* ed    = (const int*)d_in[4];
    const float* ew  = (const float*)d_in[5];
    const float* ue  = (const float*)d_in[6];
    const float* ie  = (const float*)d_in[7];
    const float* cf  = (const float*)d_in[8];
    const float* Wp  = (const float*)d_in[9];
    const float* bp  = (const float*)d_in[10];
    const float* wg  = (const float*)d_in[11];
    const float* bg  = (const float*)d_in[12];
    float* out = (float*)d_out;

    // ---- workspace layout (~103 MB) ----
    unsigned short* embA = (unsigned short*)d_ws;             // 19.2 MB
    unsigned short* embB = embA + (size_t)N_NODES * DD;       // 19.2 MB
    float* acc_items = (float*)(embB + (size_t)N_NODES * DD); // 12.8 MB
    float* ic        = acc_items + (size_t)N_ITEMS * DD;      // 12.8 MB
    float* loss_slot = ic + (size_t)N_ITEMS * DD;             // 64 B
    int*   cursor    = (int*)(loss_slot + 16);                // 600 KB
    int*   partials  = cursor + 150016;                       // 1 KB
    int*   bucket_cursor = partials + 256;                    // 1 KB
    uint2* adj       = (uint2*)(bucket_cursor + 256);         // 38.4 MB
    // binned scratch overlaps embB..ic (dead after scatter_k; CSR build
    // runs BEFORE content_combine_k / embB use). 38.4 MB <= 44.8 MB region.
    uint2* binned    = (uint2*)embB;

    hipMemsetAsync(cursor, 0, 150016 * sizeof(int), stream);
    hipMemsetAsync(loss_slot, 0, sizeof(float), stream);

    // ---- CSR build first (binned scratch overlaps later-written buffers) ----
    hist_k<<<(N_EDGES_C / 4 + 255) / 256, 256, 0, stream>>>(ed, cursor);
    scan_blocksum_k<<<SCAN_NBLK, SCAN_BLK, 0, stream>>>(cursor, partials);
    scan_partials_k<<<1, 256, 0, stream>>>(partials);
    scan_write_k<<<SCAN_NBLK, SCAN_BLK, 0, stream>>>(partials, cursor);
    bucket_init_k<<<1, 256, 0, stream>>>(cursor, bucket_cursor);
    bin_k<<<(N_EDGES_C + BIN_TILE - 1) / BIN_TILE, 256, 0, stream>>>(
        ed, es, ew, bucket_cursor, binned);
    scatter_k<<<NBUCK, 256, 0, stream>>>(binned, cursor, adj);

    // ---- embeddings / content path ----
    init_users_k<<<(N_USERS * DD / 4) / 256, 256, 0, stream>>>(ue, embA);
    content_combine_k<<<N_ITEMS / 16, 256, 0, stream>>>(cf, Wp, bp, wg, bg, ie,
                                                        ic, embA, acc_items);
    gather_acc_k<<<3 * BATCH * DD / 256, 256, 0, stream>>>(users, pos, neg,
                                                           embA, out, 1);

    // 3 propagation layers, ping-pong
    unsigned short* cur = embA;
    unsigned short* nxt = embB;
    for (int l = 0; l < 3; ++l) {
        agg_ln_k<<<N_NODES / 4, 256, 0, stream>>>(cur, nxt, acc_items,
                                                  cursor, adj);
        gather_acc_k<<<3 * BATCH * DD / 256, 256, 0, stream>>>(users, pos, neg,
                                                               nxt, out, 0);
        unsigned short* t = cur; cur = nxt; nxt = t;
    }

    loss_k<<<2048, 256, 0, stream>>>(acc_items, ic, loss_slot);
    final_out_k<<<3 * BATCH * DD / 256, 256, 0, stream>>>(loss_slot, out);
}

// Round 2
// 1232.261 us; speedup vs baseline: 1.3977x; 1.1938x over previous
//
#include <hip/hip_runtime.h>
#include <hip/hip_bf16.h>

#define N_USERS 100000
#define N_ITEMS 50000
#define N_NODES 150000
#define DD 64
#define FF 768
#define N_EDGES_C 4800000
#define BATCH 4096
#define LN_EPS 1e-5f
#define CONTENT_LOSS_W 0.1f

#define SCAN_BLK 1024
#define SCAN_NBLK 147   // ceil(150000/1024)

#define NBUCK 147       // ceil(150000/1024) - 1024-node buckets
#define BIN_TILE 4096

#define KWIN 24         // 768 / 32 K-windows

typedef __attribute__((ext_vector_type(8))) short short8;
typedef __attribute__((ext_vector_type(4))) float f32x4;

__device__ inline float b2f(unsigned short v) {
    union { unsigned int i; float f; } u;
    u.i = ((unsigned int)v) << 16;
    return u.f;
}
__device__ inline unsigned short f2b(float f) {
    union { float f; unsigned int i; } u; u.f = f;
    unsigned int r = u.i + 0x7fff + ((u.i >> 16) & 1);   // RNE
    return (unsigned short)(r >> 16);
}
__device__ inline short bfc(float f) {
    __hip_bfloat16 h = __float2bfloat16(f);   // compiler emits v_cvt_pk_bf16_f32
    return *reinterpret_cast<short*>(&h);
}

// ---------------------------------------------------------------------------
// K1: user emb init f32 -> bf16
// ---------------------------------------------------------------------------
__global__ __launch_bounds__(256) void init_users_k(
    const float* __restrict__ ue, unsigned short* __restrict__ emb)
{
    int gid = blockIdx.x * 256 + threadIdx.x;   // N_USERS*DD/4 threads
    size_t base = (size_t)gid * 4;
    float4 v = *reinterpret_cast<const float4*>(ue + base);
    ushort4 o;
    o.x = f2b(v.x); o.y = f2b(v.y); o.z = f2b(v.z); o.w = f2b(v.w);
    *reinterpret_cast<ushort4*>(emb + base) = o;
}

// ---------------------------------------------------------------------------
// Wp (f32 [768][64]) -> bf16 B-fragment-staged layout for mfma 16x16x32.
// bstg index: (((kw*4)+nt)*64 + lane)*8 + e
//   holds Wp[kw*32 + (lane>>4)*8 + e][nt*16 + (lane&15)]
// ---------------------------------------------------------------------------
__global__ __launch_bounds__(256) void wp_stage_k(
    const float* __restrict__ Wp, unsigned short* __restrict__ bstg)
{
    int tid = blockIdx.x * 256 + threadIdx.x;   // 49152 threads
    int e    = tid & 7;
    int lane = (tid >> 3) & 63;
    int nt   = (tid >> 9) & 3;
    int kw   = tid >> 11;
    int k = kw * 32 + ((lane >> 4) << 3) + e;
    int n = nt * 16 + (lane & 15);
    bstg[tid] = (unsigned short)bfc(Wp[k * DD + n]);
}

// ---------------------------------------------------------------------------
// K2: content projection (bf16 MFMA) + f32 gate + combine.  Zero LDS.
// Each wave owns 16 rows (wave-tile).  3125 wave-tiles total (50000/16).
// A-frag (16x32): lane holds row=lane&15, k=(lane>>4)*8+e  (loaded f32,
// converted in-register).  Gate dot computed from the same f32 values.
// ---------------------------------------------------------------------------
__global__ __launch_bounds__(256) void content_mfma_k(
    const float* __restrict__ cf, const unsigned short* __restrict__ bstg,
    const float* __restrict__ bp, const float* __restrict__ wg,
    const float* __restrict__ bg, const float* __restrict__ item_emb,
    float* __restrict__ items_content,
    unsigned short* __restrict__ emb, float* __restrict__ acc_items)
{
    const int wt = blockIdx.x * 4 + (threadIdx.x >> 6);
    if (wt >= N_ITEMS / 16) return;
    const int lane = threadIdx.x & 63;
    const int row0 = wt * 16;

    const int lrow = lane & 15;          // row within tile (A operand)
    const int kgrp = lane >> 4;          // k-chunk 0..3

    const float* aptr = cf + (size_t)(row0 + lrow) * FF + (kgrp << 3);
    const float* wptr = wg + (kgrp << 3);
    const short8* bptr = reinterpret_cast<const short8*>(bstg) + lane;

    f32x4 acc0 = {0.f, 0.f, 0.f, 0.f};
    f32x4 acc1 = {0.f, 0.f, 0.f, 0.f};
    f32x4 acc2 = {0.f, 0.f, 0.f, 0.f};
    f32x4 acc3 = {0.f, 0.f, 0.f, 0.f};
    float gp = 0.f;

    #pragma unroll 4
    for (int kw = 0; kw < KWIN; ++kw) {
        float4 a0 = *reinterpret_cast<const float4*>(aptr + kw * 32);
        float4 a1 = *reinterpret_cast<const float4*>(aptr + kw * 32 + 4);
        float4 w0 = *reinterpret_cast<const float4*>(wptr + kw * 32);
        float4 w1 = *reinterpret_cast<const float4*>(wptr + kw * 32 + 4);

        gp += a0.x * w0.x + a0.y * w0.y + a0.z * w0.z + a0.w * w0.w;
        gp += a1.x * w1.x + a1.y * w1.y + a1.z * w1.z + a1.w * w1.w;

        short8 af;
        af[0] = bfc(a0.x); af[1] = bfc(a0.y); af[2] = bfc(a0.z); af[3] = bfc(a0.w);
        af[4] = bfc(a1.x); af[5] = bfc(a1.y); af[6] = bfc(a1.z); af[7] = bfc(a1.w);

        const short8* bb = bptr + (size_t)kw * 256;   // (kw*4+nt)*64+lane
        short8 b0 = bb[0];
        short8 b1 = bb[64];
        short8 b2 = bb[128];
        short8 b3 = bb[192];

        acc0 = __builtin_amdgcn_mfma_f32_16x16x32_bf16(af, b0, acc0, 0, 0, 0);
        acc1 = __builtin_amdgcn_mfma_f32_16x16x32_bf16(af, b1, acc1, 0, 0, 0);
        acc2 = __builtin_amdgcn_mfma_f32_16x16x32_bf16(af, b2, acc2, 0, 0, 0);
        acc3 = __builtin_amdgcn_mfma_f32_16x16x32_bf16(af, b3, acc3, 0, 0, 0);
    }

    // gate: lanes {l, l^16, l^32, l^48} hold k-partials for row lane&15
    gp += __shfl_xor(gp, 16);
    gp += __shfl_xor(gp, 32);
    const float g = 1.f / (1.f + __expf(-(gp + bg[0])));

    // epilogue: C layout col=lane&15, row=(lane>>4)*4+reg
    const int rbase = kgrp << 2;
    f32x4 accs[4] = {acc0, acc1, acc2, acc3};
    #pragma unroll
    for (int nt = 0; nt < 4; ++nt) {
        const int col = nt * 16 + lrow;
        const float bpv = bp[col];
        #pragma unroll
        for (int r = 0; r < 4; ++r) {
            const int rit = rbase + r;
            const int row = row0 + rit;
            const float ic = accs[nt][r] + bpv;
            const float gr = __shfl(g, rit);
            const size_t o = (size_t)row * DD + col;
            const float it = (1.f - gr) * item_emb[o] + gr * ic;
            items_content[o] = ic;
            emb[(size_t)(N_USERS + row) * DD + col] = f2b(it);
            acc_items[o] = it;
        }
    }
}

// ---------------------------------------------------------------------------
// CSR build: histogram -> scan -> binning (2-phase, write-combined)
// ---------------------------------------------------------------------------
__global__ __launch_bounds__(256) void hist_k(
    const int* __restrict__ ed, int* __restrict__ cursor)
{
    int t = blockIdx.x * 256 + threadIdx.x;
    if (t < N_EDGES_C / 4) {
        int4 d = reinterpret_cast<const int4*>(ed)[t];
        atomicAdd(&cursor[d.x], 1);
        atomicAdd(&cursor[d.y], 1);
        atomicAdd(&cursor[d.z], 1);
        atomicAdd(&cursor[d.w], 1);
    }
}

__global__ __launch_bounds__(SCAN_BLK) void scan_blocksum_k(
    const int* __restrict__ cursor, int* __restrict__ partials)
{
    __shared__ int sdata[SCAN_BLK];
    int i = blockIdx.x * SCAN_BLK + threadIdx.x;
    int v = (i < N_NODES) ? cursor[i] : 0;
    sdata[threadIdx.x] = v;
    __syncthreads();
    for (int off = SCAN_BLK / 2; off; off >>= 1) {
        if (threadIdx.x < off) sdata[threadIdx.x] += sdata[threadIdx.x + off];
        __syncthreads();
    }
    if (threadIdx.x == 0) partials[blockIdx.x] = sdata[0];
}

__global__ __launch_bounds__(256) void scan_partials_k(int* __restrict__ partials)
{
    __shared__ int sdata[256];
    int t = threadIdx.x;
    int v = (t < SCAN_NBLK) ? partials[t] : 0;
    sdata[t] = v;
    __syncthreads();
    for (int off = 1; off < 256; off <<= 1) {
        int x = (t >= off) ? sdata[t - off] : 0;
        __syncthreads();
        sdata[t] += x;
        __syncthreads();
    }
    if (t < SCAN_NBLK) partials[t] = sdata[t] - v;   // exclusive
}

__global__ __launch_bounds__(SCAN_BLK) void scan_write_k(
    const int* __restrict__ partials, int* __restrict__ cursor)
{
    __shared__ int sdata[SCAN_BLK];
    int i = blockIdx.x * SCAN_BLK + threadIdx.x;
    int t = threadIdx.x;
    int v = (i < N_NODES) ? cursor[i] : 0;
    sdata[t] = v;
    __syncthreads();
    for (int off = 1; off < SCAN_BLK; off <<= 1) {
        int x = (t >= off) ? sdata[t - off] : 0;
        __syncthreads();
        sdata[t] += x;
        __syncthreads();
    }
    if (i < N_NODES)
        cursor[i] = partials[blockIdx.x] + sdata[t] - v;   // exclusive start
}

// bucket_cursor[b] = start offset of bucket b (= cursor at 1024-node bounds)
__global__ __launch_bounds__(256) void bucket_init_k(
    const int* __restrict__ cursor, int* __restrict__ bucket_cursor)
{
    int t = threadIdx.x;
    if (t < NBUCK) bucket_cursor[t] = cursor[t << 10];
}

// Pass A: tile-sort edges into 147 coarse buckets with LDS write combining.
// binned entry: x = (src<<10)|(dst&1023), y = weight bits
__global__ __launch_bounds__(256) void bin_k(
    const int* __restrict__ ed, const int* __restrict__ es,
    const float* __restrict__ ew, int* __restrict__ bucket_cursor,
    uint2* __restrict__ binned)
{
    __shared__ uint2 stage[BIN_TILE];        // 32 KB
    __shared__ int h[NBUCK];                 // hist, then running cursor
    __shared__ int o[NBUCK];                 // exclusive offsets
    __shared__ int gbase[NBUCK];
    __shared__ int scanbuf[256];

    const int t = threadIdx.x;
    const int base = blockIdx.x * BIN_TILE;
    const int cnt = min(BIN_TILE, N_EDGES_C - base);

    for (int i = t; i < NBUCK; i += 256) h[i] = 0;
    __syncthreads();

    int ld[16]; int ls[16]; float lw[16]; int lb[16];
    #pragma unroll
    for (int k = 0; k < 16; ++k) {
        int i = t + k * 256;
        if (i < cnt) {
            int d = ed[base + i];
            ld[k] = d;
            ls[k] = es[base + i];
            lw[k] = ew[base + i];
            int b = d >> 10;
            lb[k] = b;
            atomicAdd(&h[b], 1);
        } else lb[k] = -1;
    }
    __syncthreads();

    // exclusive scan of h -> o (NBUCK <= 256)
    {
        int v = (t < NBUCK) ? h[t] : 0;
        scanbuf[t] = v;
        __syncthreads();
        for (int off = 1; off < 256; off <<= 1) {
            int x = (t >= off) ? scanbuf[t - off] : 0;
            __syncthreads();
            scanbuf[t] += x;
            __syncthreads();
        }
        if (t < NBUCK) o[t] = scanbuf[t] - v;
    }
    __syncthreads();

    if (t < NBUCK) h[t] = o[t];   // running cursors
    __syncthreads();

    #pragma unroll
    for (int k = 0; k < 16; ++k) {
        if (lb[k] >= 0) {
            int p = atomicAdd(&h[lb[k]], 1);
            unsigned key = ((unsigned)ls[k] << 10) | (unsigned)(ld[k] & 1023);
            stage[p] = make_uint2(key, __float_as_uint(lw[k]));
        }
    }
    __syncthreads();

    // reserve contiguous global space per bucket (h now = end offsets)
    if (t < NBUCK) {
        int c = h[t] - o[t];
        gbase[t] = (c > 0) ? atomicAdd(&bucket_cursor[t], c) : 0;
    }
    __syncthreads();

    // copy out, coalesced within bucket segments
    for (int i = t; i < cnt; i += 256) {
        int lo = 0, hi = NBUCK - 1;          // largest b with o[b] <= i
        while (lo < hi) {
            int mid = (lo + hi + 1) >> 1;
            if (o[mid] <= i) lo = mid; else hi = mid - 1;
        }
        binned[gbase[lo] + (i - o[lo])] = stage[i];
    }
}

// Pass B: one block owns one 1024-node bucket; scatter to final CSR slots.
// All writes land in one 261KB region owned by this block -> L2 combining.
__global__ __launch_bounds__(256) void scatter_k(
    const uint2* __restrict__ binned, const int* __restrict__ cursor,
    uint2* __restrict__ adj)
{
    __shared__ int lc[1024];
    const int b = blockIdx.x;
    const int t = threadIdx.x;
    const int nb = b << 10;
    for (int j = t; j < 1024; j += 256) {
        int n = nb + j;
        lc[j] = (n < N_NODES) ? cursor[n] : 0;
    }
    __syncthreads();
    const int s0 = cursor[nb];
    const int s1 = (b == NBUCK - 1) ? N_EDGES_C : cursor[nb + 1024];
    for (int i = s0 + t; i < s1; i += 256) {
        uint2 e = binned[i];
        int ln = (int)(e.x & 1023u);
        unsigned src = e.x >> 10;
        int p = atomicAdd(&lc[ln], 1);
        adj[p] = make_uint2(src, e.y);
    }
}

// ---------------------------------------------------------------------------
// K3: fused aggregate + layernorm + residual (bf16 emb state)
// cursor holds exclusive START offsets (unchanged by build).
// ---------------------------------------------------------------------------
__global__ __launch_bounds__(256) void agg_ln_k(
    const unsigned short* __restrict__ emb_in,
    unsigned short* __restrict__ emb_out,
    float* __restrict__ acc_items,
    const int* __restrict__ cursor, const uint2* __restrict__ adj)
{
    int n = blockIdx.x * 4 + (threadIdx.x >> 6);   // 37500 blocks exact
    int lane = threadIdx.x & 63;
    int beg = cursor[n];
    int end = (n == N_NODES - 1) ? N_EDGES_C : cursor[n + 1];

    float a = 0.f;
    int j = beg;
    for (; j + 3 < end; j += 4) {
        uint2 e0 = adj[j], e1 = adj[j + 1], e2 = adj[j + 2], e3 = adj[j + 3];
        float v0 = b2f(emb_in[(size_t)e0.x * DD + lane]);
        float v1 = b2f(emb_in[(size_t)e1.x * DD + lane]);
        float v2 = b2f(emb_in[(size_t)e2.x * DD + lane]);
        float v3 = b2f(emb_in[(size_t)e3.x * DD + lane]);
        a += __uint_as_float(e0.y) * v0;
        a += __uint_as_float(e1.y) * v1;
        a += __uint_as_float(e2.y) * v2;
        a += __uint_as_float(e3.y) * v3;
    }
    for (; j < end; ++j) {
        uint2 e0 = adj[j];
        a += __uint_as_float(e0.y) * b2f(emb_in[(size_t)e0.x * DD + lane]);
    }

    float s = a;
    #pragma unroll
    for (int off = 32; off; off >>= 1) s += __shfl_xor(s, off);
    float m = s * (1.f / 64.f);
    float dlt = a - m;
    float vv = dlt * dlt;
    #pragma unroll
    for (int off = 32; off; off >>= 1) vv += __shfl_xor(vv, off);
    float var = vv * (1.f / 64.f);
    float y = dlt * rsqrtf(var + LN_EPS);

    size_t o = (size_t)n * DD + lane;
    float e_new = y + b2f(emb_in[o]);
    emb_out[o] = f2b(e_new);
    if (n >= N_USERS)
        acc_items[(size_t)(n - N_USERS) * DD + lane] += e_new;
}

// ---------------------------------------------------------------------------
// K4: accumulate sampled rows directly into out
// ---------------------------------------------------------------------------
__global__ __launch_bounds__(256) void gather_acc_k(
    const int* __restrict__ users, const int* __restrict__ pos,
    const int* __restrict__ neg, const unsigned short* __restrict__ emb_state,
    float* __restrict__ out, int init)
{
    int gid = blockIdx.x * 256 + threadIdx.x;   // 3*BATCH*DD = 786432
    int part = gid / (BATCH * DD);
    int r = gid - part * (BATCH * DD);
    int b = r >> 6, c = r & 63;
    int node;
    if (part == 0)      node = users[b];
    else if (part == 1) node = N_USERS + pos[b];
    else                node = N_USERS + neg[b];
    float v = b2f(emb_state[(size_t)node * DD + c]);
    if (init) out[gid] = v;
    else      out[gid] += v;
}

// ---------------------------------------------------------------------------
// K5: content loss
// ---------------------------------------------------------------------------
__global__ __launch_bounds__(256) void loss_k(
    const float* __restrict__ acc_items, const float* __restrict__ ic,
    float* __restrict__ loss_slot)
{
    const int total = N_ITEMS * DD;
    int stride = gridDim.x * 256;
    float p = 0.f;
    for (int i = blockIdx.x * 256 + threadIdx.x; i < total; i += stride) {
        float d = acc_items[i] * 0.25f - ic[i];
        p += d * d;
    }
    #pragma unroll
    for (int off = 32; off; off >>= 1) p += __shfl_xor(p, off);
    __shared__ float red[4];
    if ((threadIdx.x & 63) == 0) red[threadIdx.x >> 6] = p;
    __syncthreads();
    if (threadIdx.x == 0)
        atomicAdd(loss_slot, red[0] + red[1] + red[2] + red[3]);
}

// ---------------------------------------------------------------------------
// K6: out *= 0.25 ; write loss element
// ---------------------------------------------------------------------------
__global__ __launch_bounds__(256) void final_out_k(
    const float* __restrict__ loss_slot, float* __restrict__ out)
{
    int gid = blockIdx.x * 256 + threadIdx.x;
    out[gid] *= 0.25f;
    if (gid == 0)
        out[3 * BATCH * DD] =
            loss_slot[0] * (CONTENT_LOSS_W / (float)(N_ITEMS * DD));
}

// ---------------------------------------------------------------------------
extern "C" void kernel_launch(void* const* d_in, const int* in_sizes, int n_in,
                              void* d_out, int out_size, void* d_ws, size_t ws_size,
                              hipStream_t stream)
{
    const int* users = (const int*)d_in[0];
    const int* pos   = (const int*)d_in[1];
    const int* neg   = (const int*)d_in[2];
    const int* es    = (const int*)d_in[3];
    const int* ed    = (const int*)d_in[4];
    const float* ew  = (const float*)d_in[5];
    const float* ue  = (const float*)d_in[6];
    const float* ie  = (const float*)d_in[7];
    const float* cf  = (const float*)d_in[8];
    const float* Wp  = (const float*)d_in[9];
    const float* bp  = (const float*)d_in[10];
    const float* wg  = (const float*)d_in[11];
    const float* bg  = (const float*)d_in[12];
    float* out = (float*)d_out;

    // ---- workspace layout (~103 MB) ----
    unsigned short* embA = (unsigned short*)d_ws;             // 19.2 MB
    unsigned short* embB = embA + (size_t)N_NODES * DD;       // 19.2 MB
    float* acc_items = (float*)(embB + (size_t)N_NODES * DD); // 12.8 MB
    float* ic        = acc_items + (size_t)N_ITEMS * DD;      // 12.8 MB
    float* loss_slot = ic + (size_t)N_ITEMS * DD;             // 64 B
    int*   cursor    = (int*)(loss_slot + 16);                // 600 KB
    int*   partials  = cursor + 150016;                       // 1 KB
    int*   bucket_cursor = partials + 256;                    // 1 KB
    uint2* adj       = (uint2*)(bucket_cursor + 256);         // 38.4 MB
    // binned scratch overlaps embB..ic (dead after scatter_k; CSR build
    // runs BEFORE content path / embB use). 38.4 MB <= 44.8 MB region.
    uint2* binned    = (uint2*)embB;
    // bstg (96 KB) parked in embA's USER region: content_mfma_k reads it
    // while writing only the ITEM region of embA; init_users_k overwrites
    // it afterwards (bstg dead by then). Zero workspace growth.
    unsigned short* bstg = embA;

    hipMemsetAsync(cursor, 0, 150016 * sizeof(int), stream);
    hipMemsetAsync(loss_slot, 0, sizeof(float), stream);

    // ---- CSR build first (binned scratch overlaps later-written buffers) ----
    hist_k<<<(N_EDGES_C / 4 + 255) / 256, 256, 0, stream>>>(ed, cursor);
    scan_blocksum_k<<<SCAN_NBLK, SCAN_BLK, 0, stream>>>(cursor, partials);
    scan_partials_k<<<1, 256, 0, stream>>>(partials);
    scan_write_k<<<SCAN_NBLK, SCAN_BLK, 0, stream>>>(partials, cursor);
    bucket_init_k<<<1, 256, 0, stream>>>(cursor, bucket_cursor);
    bin_k<<<(N_EDGES_C + BIN_TILE - 1) / BIN_TILE, 256, 0, stream>>>(
        ed, es, ew, bucket_cursor, binned);
    scatter_k<<<NBUCK, 256, 0, stream>>>(binned, cursor, adj);

    // ---- content path (MFMA), then user init overwrites bstg ----
    wp_stage_k<<<192, 256, 0, stream>>>(Wp, bstg);
    content_mfma_k<<<(N_ITEMS / 16 + 3) / 4, 256, 0, stream>>>(
        cf, bstg, bp, wg, bg, ie, ic, embA, acc_items);
    init_users_k<<<(N_USERS * DD / 4) / 256, 256, 0, stream>>>(ue, embA);
    gather_acc_k<<<3 * BATCH * DD / 256, 256, 0, stream>>>(users, pos, neg,
                                                           embA, out, 1);

    // 3 propagation layers, ping-pong
    unsigned short* cur = embA;
    unsigned short* nxt = embB;
    for (int l = 0; l < 3; ++l) {
        agg_ln_k<<<N_NODES / 4, 256, 0, stream>>>(cur, nxt, acc_items,
                                                  cursor, adj);
        gather_acc_k<<<3 * BATCH * DD / 256, 256, 0, stream>>>(users, pos, neg,
                                                               nxt, out, 0);
        unsigned short* t = cur; cur = nxt; nxt = t;
    }

    loss_k<<<2048, 256, 0, stream>>>(acc_items, ic, loss_slot);
    final_out_k<<<3 * BATCH * DD / 256, 256, 0, stream>>>(loss_slot, out);
}

// Round 3
// 1004.280 us; speedup vs baseline: 1.7150x; 1.2270x over previous
//
#include <hip/hip_runtime.h>
#include <hip/hip_bf16.h>

#define N_USERS 100000
#define N_ITEMS 50000
#define N_NODES 150000
#define DD 64
#define FF 768
#define N_EDGES_C 4800000
#define BATCH 4096
#define LN_EPS 1e-5f
#define CONTENT_LOSS_W 0.1f

#define SCAN_BLK 1024
#define SCAN_NBLK 147   // ceil(150000/1024)

#define NBUCK 147       // ceil(150000/1024) - 1024-node buckets
#define BIN_TILE 4096

#define KWIN 24         // 768 / 32 K-windows

typedef __attribute__((ext_vector_type(8))) short short8;
typedef __attribute__((ext_vector_type(4))) float f32x4;

__device__ inline float b2f(unsigned short v) {
    union { unsigned int i; float f; } u;
    u.i = ((unsigned int)v) << 16;
    return u.f;
}
__device__ inline unsigned short f2b(float f) {
    union { float f; unsigned int i; } u; u.f = f;
    unsigned int r = u.i + 0x7fff + ((u.i >> 16) & 1);   // RNE
    return (unsigned short)(r >> 16);
}
__device__ inline short bfc(float f) {
    __hip_bfloat16 h = __float2bfloat16(f);   // compiler emits v_cvt_pk_bf16_f32
    return *reinterpret_cast<short*>(&h);
}

// ---------------------------------------------------------------------------
// K1: user emb init f32 -> bf16
// ---------------------------------------------------------------------------
__global__ __launch_bounds__(256) void init_users_k(
    const float* __restrict__ ue, unsigned short* __restrict__ emb)
{
    int gid = blockIdx.x * 256 + threadIdx.x;   // N_USERS*DD/4 threads
    size_t base = (size_t)gid * 4;
    float4 v = *reinterpret_cast<const float4*>(ue + base);
    ushort4 o;
    o.x = f2b(v.x); o.y = f2b(v.y); o.z = f2b(v.z); o.w = f2b(v.w);
    *reinterpret_cast<ushort4*>(emb + base) = o;
}

// ---------------------------------------------------------------------------
// Wp (f32 [768][64]) -> bf16 B-fragment-staged layout for mfma 16x16x32.
// bstg index: (((kw*4)+nt)*64 + lane)*8 + e
//   holds Wp[kw*32 + (lane>>4)*8 + e][nt*16 + (lane&15)]
// ---------------------------------------------------------------------------
__global__ __launch_bounds__(256) void wp_stage_k(
    const float* __restrict__ Wp, unsigned short* __restrict__ bstg)
{
    int tid = blockIdx.x * 256 + threadIdx.x;   // 49152 threads
    int e    = tid & 7;
    int lane = (tid >> 3) & 63;
    int nt   = (tid >> 9) & 3;
    int kw   = tid >> 11;
    int k = kw * 32 + ((lane >> 4) << 3) + e;
    int n = nt * 16 + (lane & 15);
    bstg[tid] = (unsigned short)bfc(Wp[k * DD + n]);
}

// ---------------------------------------------------------------------------
// K2: content projection (bf16 MFMA) + f32 gate + combine.  Zero LDS.
// ---------------------------------------------------------------------------
__global__ __launch_bounds__(256) void content_mfma_k(
    const float* __restrict__ cf, const unsigned short* __restrict__ bstg,
    const float* __restrict__ bp, const float* __restrict__ wg,
    const float* __restrict__ bg, const float* __restrict__ item_emb,
    float* __restrict__ items_content,
    unsigned short* __restrict__ emb, float* __restrict__ acc_items)
{
    const int wt = blockIdx.x * 4 + (threadIdx.x >> 6);
    if (wt >= N_ITEMS / 16) return;
    const int lane = threadIdx.x & 63;
    const int row0 = wt * 16;

    const int lrow = lane & 15;          // row within tile (A operand)
    const int kgrp = lane >> 4;          // k-chunk 0..3

    const float* aptr = cf + (size_t)(row0 + lrow) * FF + (kgrp << 3);
    const float* wptr = wg + (kgrp << 3);
    const short8* bptr = reinterpret_cast<const short8*>(bstg) + lane;

    f32x4 acc0 = {0.f, 0.f, 0.f, 0.f};
    f32x4 acc1 = {0.f, 0.f, 0.f, 0.f};
    f32x4 acc2 = {0.f, 0.f, 0.f, 0.f};
    f32x4 acc3 = {0.f, 0.f, 0.f, 0.f};
    float gp = 0.f;

    #pragma unroll 4
    for (int kw = 0; kw < KWIN; ++kw) {
        float4 a0 = *reinterpret_cast<const float4*>(aptr + kw * 32);
        float4 a1 = *reinterpret_cast<const float4*>(aptr + kw * 32 + 4);
        float4 w0 = *reinterpret_cast<const float4*>(wptr + kw * 32);
        float4 w1 = *reinterpret_cast<const float4*>(wptr + kw * 32 + 4);

        gp += a0.x * w0.x + a0.y * w0.y + a0.z * w0.z + a0.w * w0.w;
        gp += a1.x * w1.x + a1.y * w1.y + a1.z * w1.z + a1.w * w1.w;

        short8 af;
        af[0] = bfc(a0.x); af[1] = bfc(a0.y); af[2] = bfc(a0.z); af[3] = bfc(a0.w);
        af[4] = bfc(a1.x); af[5] = bfc(a1.y); af[6] = bfc(a1.z); af[7] = bfc(a1.w);

        const short8* bb = bptr + (size_t)kw * 256;   // (kw*4+nt)*64+lane
        short8 b0 = bb[0];
        short8 b1 = bb[64];
        short8 b2 = bb[128];
        short8 b3 = bb[192];

        acc0 = __builtin_amdgcn_mfma_f32_16x16x32_bf16(af, b0, acc0, 0, 0, 0);
        acc1 = __builtin_amdgcn_mfma_f32_16x16x32_bf16(af, b1, acc1, 0, 0, 0);
        acc2 = __builtin_amdgcn_mfma_f32_16x16x32_bf16(af, b2, acc2, 0, 0, 0);
        acc3 = __builtin_amdgcn_mfma_f32_16x16x32_bf16(af, b3, acc3, 0, 0, 0);
    }

    // gate: lanes {l, l^16, l^32, l^48} hold k-partials for row lane&15
    gp += __shfl_xor(gp, 16);
    gp += __shfl_xor(gp, 32);
    const float g = 1.f / (1.f + __expf(-(gp + bg[0])));

    // epilogue: C layout col=lane&15, row=(lane>>4)*4+reg
    const int rbase = kgrp << 2;
    f32x4 accs[4] = {acc0, acc1, acc2, acc3};
    #pragma unroll
    for (int nt = 0; nt < 4; ++nt) {
        const int col = nt * 16 + lrow;
        const float bpv = bp[col];
        #pragma unroll
        for (int r = 0; r < 4; ++r) {
            const int rit = rbase + r;
            const int row = row0 + rit;
            const float ic = accs[nt][r] + bpv;
            const float gr = __shfl(g, rit);
            const size_t o = (size_t)row * DD + col;
            const float it = (1.f - gr) * item_emb[o] + gr * ic;
            items_content[o] = ic;
            emb[(size_t)(N_USERS + row) * DD + col] = f2b(it);
            acc_items[o] = it;
        }
    }
}

// ---------------------------------------------------------------------------
// CSR build: histogram -> scan -> binning (2-phase, write-combined)
// ---------------------------------------------------------------------------
__global__ __launch_bounds__(256) void hist_k(
    const int* __restrict__ ed, int* __restrict__ cursor)
{
    int t = blockIdx.x * 256 + threadIdx.x;
    if (t < N_EDGES_C / 4) {
        int4 d = reinterpret_cast<const int4*>(ed)[t];
        atomicAdd(&cursor[d.x], 1);
        atomicAdd(&cursor[d.y], 1);
        atomicAdd(&cursor[d.z], 1);
        atomicAdd(&cursor[d.w], 1);
    }
}

__global__ __launch_bounds__(SCAN_BLK) void scan_blocksum_k(
    const int* __restrict__ cursor, int* __restrict__ partials)
{
    __shared__ int sdata[SCAN_BLK];
    int i = blockIdx.x * SCAN_BLK + threadIdx.x;
    int v = (i < N_NODES) ? cursor[i] : 0;
    sdata[threadIdx.x] = v;
    __syncthreads();
    for (int off = SCAN_BLK / 2; off; off >>= 1) {
        if (threadIdx.x < off) sdata[threadIdx.x] += sdata[threadIdx.x + off];
        __syncthreads();
    }
    if (threadIdx.x == 0) partials[blockIdx.x] = sdata[0];
}

__global__ __launch_bounds__(256) void scan_partials_k(int* __restrict__ partials)
{
    __shared__ int sdata[256];
    int t = threadIdx.x;
    int v = (t < SCAN_NBLK) ? partials[t] : 0;
    sdata[t] = v;
    __syncthreads();
    for (int off = 1; off < 256; off <<= 1) {
        int x = (t >= off) ? sdata[t - off] : 0;
        __syncthreads();
        sdata[t] += x;
        __syncthreads();
    }
    if (t < SCAN_NBLK) partials[t] = sdata[t] - v;   // exclusive
}

__global__ __launch_bounds__(SCAN_BLK) void scan_write_k(
    const int* __restrict__ partials, int* __restrict__ cursor)
{
    __shared__ int sdata[SCAN_BLK];
    int i = blockIdx.x * SCAN_BLK + threadIdx.x;
    int t = threadIdx.x;
    int v = (i < N_NODES) ? cursor[i] : 0;
    sdata[t] = v;
    __syncthreads();
    for (int off = 1; off < SCAN_BLK; off <<= 1) {
        int x = (t >= off) ? sdata[t - off] : 0;
        __syncthreads();
        sdata[t] += x;
        __syncthreads();
    }
    if (i < N_NODES)
        cursor[i] = partials[blockIdx.x] + sdata[t] - v;   // exclusive start
}

// bucket_cursor[b] = start offset of bucket b (= cursor at 1024-node bounds)
__global__ __launch_bounds__(256) void bucket_init_k(
    const int* __restrict__ cursor, int* __restrict__ bucket_cursor)
{
    int t = threadIdx.x;
    if (t < NBUCK) bucket_cursor[t] = cursor[t << 10];
}

// Pass A: tile-sort edges into 147 coarse buckets with LDS write combining.
// binned entry: x = (src<<10)|(dst&1023), y = weight bits
__global__ __launch_bounds__(256) void bin_k(
    const int* __restrict__ ed, const int* __restrict__ es,
    const float* __restrict__ ew, int* __restrict__ bucket_cursor,
    uint2* __restrict__ binned)
{
    __shared__ uint2 stage[BIN_TILE];        // 32 KB
    __shared__ int h[NBUCK];                 // hist, then running cursor
    __shared__ int o[NBUCK];                 // exclusive offsets
    __shared__ int gbase[NBUCK];
    __shared__ int scanbuf[256];

    const int t = threadIdx.x;
    const int base = blockIdx.x * BIN_TILE;
    const int cnt = min(BIN_TILE, N_EDGES_C - base);

    for (int i = t; i < NBUCK; i += 256) h[i] = 0;
    __syncthreads();

    int ld[16]; int ls[16]; float lw[16]; int lb[16];
    #pragma unroll
    for (int k = 0; k < 16; ++k) {
        int i = t + k * 256;
        if (i < cnt) {
            int d = ed[base + i];
            ld[k] = d;
            ls[k] = es[base + i];
            lw[k] = ew[base + i];
            int b = d >> 10;
            lb[k] = b;
            atomicAdd(&h[b], 1);
        } else lb[k] = -1;
    }
    __syncthreads();

    // exclusive scan of h -> o (NBUCK <= 256)
    {
        int v = (t < NBUCK) ? h[t] : 0;
        scanbuf[t] = v;
        __syncthreads();
        for (int off = 1; off < 256; off <<= 1) {
            int x = (t >= off) ? scanbuf[t - off] : 0;
            __syncthreads();
            scanbuf[t] += x;
            __syncthreads();
        }
        if (t < NBUCK) o[t] = scanbuf[t] - v;
    }
    __syncthreads();

    if (t < NBUCK) h[t] = o[t];   // running cursors
    __syncthreads();

    #pragma unroll
    for (int k = 0; k < 16; ++k) {
        if (lb[k] >= 0) {
            int p = atomicAdd(&h[lb[k]], 1);
            unsigned key = ((unsigned)ls[k] << 10) | (unsigned)(ld[k] & 1023);
            stage[p] = make_uint2(key, __float_as_uint(lw[k]));
        }
    }
    __syncthreads();

    // reserve contiguous global space per bucket (h now = end offsets)
    if (t < NBUCK) {
        int c = h[t] - o[t];
        gbase[t] = (c > 0) ? atomicAdd(&bucket_cursor[t], c) : 0;
    }
    __syncthreads();

    // copy out, coalesced within bucket segments
    for (int i = t; i < cnt; i += 256) {
        int lo = 0, hi = NBUCK - 1;          // largest b with o[b] <= i
        while (lo < hi) {
            int mid = (lo + hi + 1) >> 1;
            if (o[mid] <= i) lo = mid; else hi = mid - 1;
        }
        binned[gbase[lo] + (i - o[lo])] = stage[i];
    }
}

// Pass B: one block owns one 1024-node bucket; scatter to final CSR slots.
// All writes land in one 261KB region owned by this block -> L2 combining.
__global__ __launch_bounds__(256) void scatter_k(
    const uint2* __restrict__ binned, const int* __restrict__ cursor,
    uint2* __restrict__ adj)
{
    __shared__ int lc[1024];
    const int b = blockIdx.x;
    const int t = threadIdx.x;
    const int nb = b << 10;
    for (int j = t; j < 1024; j += 256) {
        int n = nb + j;
        lc[j] = (n < N_NODES) ? cursor[n] : 0;
    }
    __syncthreads();
    const int s0 = cursor[nb];
    const int s1 = (b == NBUCK - 1) ? N_EDGES_C : cursor[nb + 1024];
    for (int i = s0 + t; i < s1; i += 256) {
        uint2 e = binned[i];
        int ln = (int)(e.x & 1023u);
        unsigned src = e.x >> 10;
        int p = atomicAdd(&lc[ln], 1);
        adj[p] = make_uint2(src, e.y);
    }
}

// ---------------------------------------------------------------------------
// K3: fused aggregate + layernorm + residual (bf16 emb state)
// 4 edge-slot groups of 16 lanes; lane covers 4 cols (ushort4 per gather).
// One gather instruction moves 4 edge-rows (512B) -> 4x MLP vs scalar form.
// ---------------------------------------------------------------------------
__global__ __launch_bounds__(256) void agg_ln_k(
    const unsigned short* __restrict__ emb_in,
    unsigned short* __restrict__ emb_out,
    float* __restrict__ acc_items,
    const int* __restrict__ cursor, const uint2* __restrict__ adj)
{
    const int n = blockIdx.x * 4 + (threadIdx.x >> 6);   // 37500 blocks exact
    const int lane = threadIdx.x & 63;
    const int g = lane >> 4;          // edge-slot group 0..3
    const int q = lane & 15;          // column quad: cols 4q..4q+3
    const int qo = q << 2;

    const int beg = cursor[n];
    const int end = (n == N_NODES - 1) ? N_EDGES_C : cursor[n + 1];

    float a0 = 0.f, a1 = 0.f, a2 = 0.f, a3 = 0.f;

    int j = beg;
    // main: 16 edges per iteration (4 chunks of 4)
    for (; j + 15 < end; j += 16) {
        uint2 e0 = adj[j + g];
        uint2 e1 = adj[j + 4 + g];
        uint2 e2 = adj[j + 8 + g];
        uint2 e3 = adj[j + 12 + g];
        ushort4 r0 = *reinterpret_cast<const ushort4*>(emb_in + (size_t)e0.x * DD + qo);
        ushort4 r1 = *reinterpret_cast<const ushort4*>(emb_in + (size_t)e1.x * DD + qo);
        ushort4 r2 = *reinterpret_cast<const ushort4*>(emb_in + (size_t)e2.x * DD + qo);
        ushort4 r3 = *reinterpret_cast<const ushort4*>(emb_in + (size_t)e3.x * DD + qo);
        float w0 = __uint_as_float(e0.y), w1 = __uint_as_float(e1.y);
        float w2 = __uint_as_float(e2.y), w3 = __uint_as_float(e3.y);
        a0 += w0 * b2f(r0.x); a1 += w0 * b2f(r0.y); a2 += w0 * b2f(r0.z); a3 += w0 * b2f(r0.w);
        a0 += w1 * b2f(r1.x); a1 += w1 * b2f(r1.y); a2 += w1 * b2f(r1.z); a3 += w1 * b2f(r1.w);
        a0 += w2 * b2f(r2.x); a1 += w2 * b2f(r2.y); a2 += w2 * b2f(r2.z); a3 += w2 * b2f(r2.w);
        a0 += w3 * b2f(r3.x); a1 += w3 * b2f(r3.y); a2 += w3 * b2f(r3.z); a3 += w3 * b2f(r3.w);
    }
    // 4-edge chunks
    for (; j + 3 < end; j += 4) {
        uint2 e = adj[j + g];
        ushort4 r = *reinterpret_cast<const ushort4*>(emb_in + (size_t)e.x * DD + qo);
        float w = __uint_as_float(e.y);
        a0 += w * b2f(r.x); a1 += w * b2f(r.y); a2 += w * b2f(r.z); a3 += w * b2f(r.w);
    }
    // tail (<4 edges): group g handles edge j+g if in range
    if (g < end - j) {
        uint2 e = adj[j + g];
        ushort4 r = *reinterpret_cast<const ushort4*>(emb_in + (size_t)e.x * DD + qo);
        float w = __uint_as_float(e.y);
        a0 += w * b2f(r.x); a1 += w * b2f(r.y); a2 += w * b2f(r.z); a3 += w * b2f(r.w);
    }

    // cross-group reduce: lanes {l, l^16, l^32, l^48} hold disjoint edge subsets
    a0 += __shfl_xor(a0, 16); a0 += __shfl_xor(a0, 32);
    a1 += __shfl_xor(a1, 16); a1 += __shfl_xor(a1, 32);
    a2 += __shfl_xor(a2, 16); a2 += __shfl_xor(a2, 32);
    a3 += __shfl_xor(a3, 16); a3 += __shfl_xor(a3, 32);

    // LN reductions over the 16 column-quads (replicated across groups)
    float s = a0 + a1 + a2 + a3;
    s += __shfl_xor(s, 1); s += __shfl_xor(s, 2);
    s += __shfl_xor(s, 4); s += __shfl_xor(s, 8);
    const float m = s * (1.f / 64.f);
    const float d0 = a0 - m, d1 = a1 - m, d2 = a2 - m, d3 = a3 - m;
    float vv = d0 * d0 + d1 * d1 + d2 * d2 + d3 * d3;
    vv += __shfl_xor(vv, 1); vv += __shfl_xor(vv, 2);
    vv += __shfl_xor(vv, 4); vv += __shfl_xor(vv, 8);
    const float rstd = rsqrtf(vv * (1.f / 64.f) + LN_EPS);

    // residual + write (group 0 only: avoids 4x duplicate stores)
    if (g == 0) {
        const size_t o = (size_t)n * DD + qo;
        ushort4 own = *reinterpret_cast<const ushort4*>(emb_in + o);
        float e0 = d0 * rstd + b2f(own.x);
        float e1 = d1 * rstd + b2f(own.y);
        float e2 = d2 * rstd + b2f(own.z);
        float e3 = d3 * rstd + b2f(own.w);
        ushort4 ob;
        ob.x = f2b(e0); ob.y = f2b(e1); ob.z = f2b(e2); ob.w = f2b(e3);
        *reinterpret_cast<ushort4*>(emb_out + o) = ob;
        if (n >= N_USERS) {
            float4* ap = reinterpret_cast<float4*>(
                acc_items + (size_t)(n - N_USERS) * DD + qo);
            float4 v = *ap;
            v.x += e0; v.y += e1; v.z += e2; v.w += e3;
            *ap = v;
        }
    }
}

// ---------------------------------------------------------------------------
// K4: accumulate sampled rows directly into out
// ---------------------------------------------------------------------------
__global__ __launch_bounds__(256) void gather_acc_k(
    const int* __restrict__ users, const int* __restrict__ pos,
    const int* __restrict__ neg, const unsigned short* __restrict__ emb_state,
    float* __restrict__ out, int init)
{
    int gid = blockIdx.x * 256 + threadIdx.x;   // 3*BATCH*DD = 786432
    int part = gid / (BATCH * DD);
    int r = gid - part * (BATCH * DD);
    int b = r >> 6, c = r & 63;
    int node;
    if (part == 0)      node = users[b];
    else if (part == 1) node = N_USERS + pos[b];
    else                node = N_USERS + neg[b];
    float v = b2f(emb_state[(size_t)node * DD + c]);
    if (init) out[gid] = v;
    else      out[gid] += v;
}

// ---------------------------------------------------------------------------
// K5: content loss
// ---------------------------------------------------------------------------
__global__ __launch_bounds__(256) void loss_k(
    const float* __restrict__ acc_items, const float* __restrict__ ic,
    float* __restrict__ loss_slot)
{
    const int total = N_ITEMS * DD;
    int stride = gridDim.x * 256;
    float p = 0.f;
    for (int i = blockIdx.x * 256 + threadIdx.x; i < total; i += stride) {
        float d = acc_items[i] * 0.25f - ic[i];
        p += d * d;
    }
    #pragma unroll
    for (int off = 32; off; off >>= 1) p += __shfl_xor(p, off);
    __shared__ float red[4];
    if ((threadIdx.x & 63) == 0) red[threadIdx.x >> 6] = p;
    __syncthreads();
    if (threadIdx.x == 0)
        atomicAdd(loss_slot, red[0] + red[1] + red[2] + red[3]);
}

// ---------------------------------------------------------------------------
// K6: out *= 0.25 ; write loss element
// ---------------------------------------------------------------------------
__global__ __launch_bounds__(256) void final_out_k(
    const float* __restrict__ loss_slot, float* __restrict__ out)
{
    int gid = blockIdx.x * 256 + threadIdx.x;
    out[gid] *= 0.25f;
    if (gid == 0)
        out[3 * BATCH * DD] =
            loss_slot[0] * (CONTENT_LOSS_W / (float)(N_ITEMS * DD));
}

// ---------------------------------------------------------------------------
extern "C" void kernel_launch(void* const* d_in, const int* in_sizes, int n_in,
                              void* d_out, int out_size, void* d_ws, size_t ws_size,
                              hipStream_t stream)
{
    const int* users = (const int*)d_in[0];
    const int* pos   = (const int*)d_in[1];
    const int* neg   = (const int*)d_in[2];
    const int* es    = (const int*)d_in[3];
    const int* ed    = (const int*)d_in[4];
    const float* ew  = (const float*)d_in[5];
    const float* ue  = (const float*)d_in[6];
    const float* ie  = (const float*)d_in[7];
    const float* cf  = (const float*)d_in[8];
    const float* Wp  = (const float*)d_in[9];
    const float* bp  = (const float*)d_in[10];
    const float* wg  = (const float*)d_in[11];
    const float* bg  = (const float*)d_in[12];
    float* out = (float*)d_out;

    // ---- workspace layout (~103 MB) ----
    unsigned short* embA = (unsigned short*)d_ws;             // 19.2 MB
    unsigned short* embB = embA + (size_t)N_NODES * DD;       // 19.2 MB
    float* acc_items = (float*)(embB + (size_t)N_NODES * DD); // 12.8 MB
    float* ic        = acc_items + (size_t)N_ITEMS * DD;      // 12.8 MB
    float* loss_slot = ic + (size_t)N_ITEMS * DD;             // 64 B
    int*   cursor    = (int*)(loss_slot + 16);                // 600 KB
    int*   partials  = cursor + 150016;                       // 1 KB
    int*   bucket_cursor = partials + 256;                    // 1 KB
    uint2* adj       = (uint2*)(bucket_cursor + 256);         // 38.4 MB
    // binned scratch overlaps embB..ic (dead after scatter_k; CSR build
    // runs BEFORE content path / embB use). 38.4 MB <= 44.8 MB region.
    uint2* binned    = (uint2*)embB;
    // bstg (96 KB) parked in embA's USER region: content_mfma_k reads it
    // while writing only the ITEM region of embA; init_users_k overwrites
    // it afterwards (bstg dead by then). Zero workspace growth.
    unsigned short* bstg = embA;

    hipMemsetAsync(cursor, 0, 150016 * sizeof(int), stream);
    hipMemsetAsync(loss_slot, 0, sizeof(float), stream);

    // ---- CSR build first (binned scratch overlaps later-written buffers) ----
    hist_k<<<(N_EDGES_C / 4 + 255) / 256, 256, 0, stream>>>(ed, cursor);
    scan_blocksum_k<<<SCAN_NBLK, SCAN_BLK, 0, stream>>>(cursor, partials);
    scan_partials_k<<<1, 256, 0, stream>>>(partials);
    scan_write_k<<<SCAN_NBLK, SCAN_BLK, 0, stream>>>(partials, cursor);
    bucket_init_k<<<1, 256, 0, stream>>>(cursor, bucket_cursor);
    bin_k<<<(N_EDGES_C + BIN_TILE - 1) / BIN_TILE, 256, 0, stream>>>(
        ed, es, ew, bucket_cursor, binned);
    scatter_k<<<NBUCK, 256, 0, stream>>>(binned, cursor, adj);

    // ---- content path (MFMA), then user init overwrites bstg ----
    wp_stage_k<<<192, 256, 0, stream>>>(Wp, bstg);
    content_mfma_k<<<(N_ITEMS / 16 + 3) / 4, 256, 0, stream>>>(
        cf, bstg, bp, wg, bg, ie, ic, embA, acc_items);
    init_users_k<<<(N_USERS * DD / 4) / 256, 256, 0, stream>>>(ue, embA);
    gather_acc_k<<<3 * BATCH * DD / 256, 256, 0, stream>>>(users, pos, neg,
                                                           embA, out, 1);

    // 3 propagation layers, ping-pong
    unsigned short* cur = embA;
    unsigned short* nxt = embB;
    for (int l = 0; l < 3; ++l) {
        agg_ln_k<<<N_NODES / 4, 256, 0, stream>>>(cur, nxt, acc_items,
                                                  cursor, adj);
        gather_acc_k<<<3 * BATCH * DD / 256, 256, 0, stream>>>(users, pos, neg,
                                                               nxt, out, 0);
        unsigned short* t = cur; cur = nxt; nxt = t;
    }

    loss_k<<<2048, 256, 0, stream>>>(acc_items, ic, loss_slot);
    final_out_k<<<3 * BATCH * DD / 256, 256, 0, stream>>>(loss_slot, out);
}

// Round 4
// 838.784 us; speedup vs baseline: 2.0534x; 1.1973x over previous
//
#include <hip/hip_runtime.h>
#include <hip/hip_bf16.h>

#define N_USERS 100000
#define N_ITEMS 50000
#define N_NODES 150000
#define DD 64
#define FF 768
#define N_EDGES_C 4800000
#define BATCH 4096
#define LN_EPS 1e-5f
#define CONTENT_LOSS_W 0.1f

#define NBUCK 147       // ceil(150000/1024) - 1024-node buckets
#define BIN_TILE 4096
#define HIST_BLKS 1200

#define KWIN 24         // 768 / 32 K-windows

typedef __attribute__((ext_vector_type(8))) short short8;
typedef __attribute__((ext_vector_type(4))) float f32x4;

__device__ inline float b2f(unsigned short v) {
    union { unsigned int i; float f; } u;
    u.i = ((unsigned int)v) << 16;
    return u.f;
}
__device__ inline unsigned short f2b(float f) {
    union { float f; unsigned int i; } u; u.f = f;
    unsigned int r = u.i + 0x7fff + ((u.i >> 16) & 1);   // RNE
    return (unsigned short)(r >> 16);
}
__device__ inline short bfc(float f) {
    __hip_bfloat16 h = __float2bfloat16(f);   // compiler emits v_cvt_pk_bf16_f32
    return *reinterpret_cast<short*>(&h);
}

// ---------------------------------------------------------------------------
// K1: user emb init f32 -> bf16
// ---------------------------------------------------------------------------
__global__ __launch_bounds__(256) void init_users_k(
    const float* __restrict__ ue, unsigned short* __restrict__ emb)
{
    int gid = blockIdx.x * 256 + threadIdx.x;   // N_USERS*DD/4 threads
    size_t base = (size_t)gid * 4;
    float4 v = *reinterpret_cast<const float4*>(ue + base);
    ushort4 o;
    o.x = f2b(v.x); o.y = f2b(v.y); o.z = f2b(v.z); o.w = f2b(v.w);
    *reinterpret_cast<ushort4*>(emb + base) = o;
}

// ---------------------------------------------------------------------------
// Wp (f32 [768][64]) -> bf16 B-fragment-staged layout for mfma 16x16x32.
// bstg index: (((kw*4)+nt)*64 + lane)*8 + e
//   holds Wp[kw*32 + (lane>>4)*8 + e][nt*16 + (lane&15)]
// ---------------------------------------------------------------------------
__global__ __launch_bounds__(256) void wp_stage_k(
    const float* __restrict__ Wp, unsigned short* __restrict__ bstg)
{
    int tid = blockIdx.x * 256 + threadIdx.x;   // 49152 threads
    int e    = tid & 7;
    int lane = (tid >> 3) & 63;
    int nt   = (tid >> 9) & 3;
    int kw   = tid >> 11;
    int k = kw * 32 + ((lane >> 4) << 3) + e;
    int n = nt * 16 + (lane & 15);
    bstg[tid] = (unsigned short)bfc(Wp[k * DD + n]);
}

// ---------------------------------------------------------------------------
// K2: content projection (bf16 MFMA) + f32 gate + combine.  Zero LDS.
// ---------------------------------------------------------------------------
__global__ __launch_bounds__(256) void content_mfma_k(
    const float* __restrict__ cf, const unsigned short* __restrict__ bstg,
    const float* __restrict__ bp, const float* __restrict__ wg,
    const float* __restrict__ bg, const float* __restrict__ item_emb,
    float* __restrict__ items_content,
    unsigned short* __restrict__ emb, float* __restrict__ acc_items)
{
    const int wt = blockIdx.x * 4 + (threadIdx.x >> 6);
    if (wt >= N_ITEMS / 16) return;
    const int lane = threadIdx.x & 63;
    const int row0 = wt * 16;

    const int lrow = lane & 15;          // row within tile (A operand)
    const int kgrp = lane >> 4;          // k-chunk 0..3

    const float* aptr = cf + (size_t)(row0 + lrow) * FF + (kgrp << 3);
    const float* wptr = wg + (kgrp << 3);
    const short8* bptr = reinterpret_cast<const short8*>(bstg) + lane;

    f32x4 acc0 = {0.f, 0.f, 0.f, 0.f};
    f32x4 acc1 = {0.f, 0.f, 0.f, 0.f};
    f32x4 acc2 = {0.f, 0.f, 0.f, 0.f};
    f32x4 acc3 = {0.f, 0.f, 0.f, 0.f};
    float gp = 0.f;

    #pragma unroll 4
    for (int kw = 0; kw < KWIN; ++kw) {
        float4 a0 = *reinterpret_cast<const float4*>(aptr + kw * 32);
        float4 a1 = *reinterpret_cast<const float4*>(aptr + kw * 32 + 4);
        float4 w0 = *reinterpret_cast<const float4*>(wptr + kw * 32);
        float4 w1 = *reinterpret_cast<const float4*>(wptr + kw * 32 + 4);

        gp += a0.x * w0.x + a0.y * w0.y + a0.z * w0.z + a0.w * w0.w;
        gp += a1.x * w1.x + a1.y * w1.y + a1.z * w1.z + a1.w * w1.w;

        short8 af;
        af[0] = bfc(a0.x); af[1] = bfc(a0.y); af[2] = bfc(a0.z); af[3] = bfc(a0.w);
        af[4] = bfc(a1.x); af[5] = bfc(a1.y); af[6] = bfc(a1.z); af[7] = bfc(a1.w);

        const short8* bb = bptr + (size_t)kw * 256;   // (kw*4+nt)*64+lane
        short8 b0 = bb[0];
        short8 b1 = bb[64];
        short8 b2 = bb[128];
        short8 b3 = bb[192];

        acc0 = __builtin_amdgcn_mfma_f32_16x16x32_bf16(af, b0, acc0, 0, 0, 0);
        acc1 = __builtin_amdgcn_mfma_f32_16x16x32_bf16(af, b1, acc1, 0, 0, 0);
        acc2 = __builtin_amdgcn_mfma_f32_16x16x32_bf16(af, b2, acc2, 0, 0, 0);
        acc3 = __builtin_amdgcn_mfma_f32_16x16x32_bf16(af, b3, acc3, 0, 0, 0);
    }

    // gate: lanes {l, l^16, l^32, l^48} hold k-partials for row lane&15
    gp += __shfl_xor(gp, 16);
    gp += __shfl_xor(gp, 32);
    const float g = 1.f / (1.f + __expf(-(gp + bg[0])));

    // epilogue: C layout col=lane&15, row=(lane>>4)*4+reg
    const int rbase = kgrp << 2;
    f32x4 accs[4] = {acc0, acc1, acc2, acc3};
    #pragma unroll
    for (int nt = 0; nt < 4; ++nt) {
        const int col = nt * 16 + lrow;
        const float bpv = bp[col];
        #pragma unroll
        for (int r = 0; r < 4; ++r) {
            const int rit = rbase + r;
            const int row = row0 + rit;
            const float ic = accs[nt][r] + bpv;
            const float gr = __shfl(g, rit);
            const size_t o = (size_t)row * DD + col;
            const float it = (1.f - gr) * item_emb[o] + gr * ic;
            items_content[o] = ic;
            emb[(size_t)(N_USERS + row) * DD + col] = f2b(it);
            acc_items[o] = it;
        }
    }
}

// ---------------------------------------------------------------------------
// CSR build v3: coarse bucket hist (LDS-privatized, no fine global atomics)
//   -> 147-scan -> bin (write-combined) -> per-bucket scatter that derives
//   per-node cursors in LDS and emits the global cursor array.
// ---------------------------------------------------------------------------
__global__ __launch_bounds__(256) void bucket_hist_k(
    const int* __restrict__ ed, int* __restrict__ bucket_cnt)
{
    __shared__ int lh[NBUCK];
    for (int i = threadIdx.x; i < NBUCK; i += 256) lh[i] = 0;
    __syncthreads();
    const int stride = HIST_BLKS * 256;
    for (int t = blockIdx.x * 256 + threadIdx.x; t < N_EDGES_C / 4; t += stride) {
        int4 d = reinterpret_cast<const int4*>(ed)[t];
        atomicAdd(&lh[d.x >> 10], 1);
        atomicAdd(&lh[d.y >> 10], 1);
        atomicAdd(&lh[d.z >> 10], 1);
        atomicAdd(&lh[d.w >> 10], 1);
    }
    __syncthreads();
    for (int i = threadIdx.x; i < NBUCK; i += 256) {
        int c = lh[i];
        if (c) atomicAdd(&bucket_cnt[i], c);
    }
}

// single block: exclusive scan of 147 bucket counts -> bucket_base[148],
// and init bucket_cursor = base.
__global__ __launch_bounds__(256) void bucket_scan_k(
    const int* __restrict__ bucket_cnt, int* __restrict__ bucket_base,
    int* __restrict__ bucket_cursor)
{
    __shared__ int sdata[256];
    int t = threadIdx.x;
    int v = (t < NBUCK) ? bucket_cnt[t] : 0;
    sdata[t] = v;
    __syncthreads();
    for (int off = 1; off < 256; off <<= 1) {
        int x = (t >= off) ? sdata[t - off] : 0;
        __syncthreads();
        sdata[t] += x;
        __syncthreads();
    }
    if (t < NBUCK) {
        int b = sdata[t] - v;   // exclusive
        bucket_base[t] = b;
        bucket_cursor[t] = b;
    }
    if (t == NBUCK - 1) bucket_base[NBUCK] = sdata[t];   // == N_EDGES_C
}

// Pass A: tile-sort edges into 147 coarse buckets with LDS write combining.
// binned entry: x = (src<<10)|(dst&1023), y = weight bits
__global__ __launch_bounds__(256) void bin_k(
    const int* __restrict__ ed, const int* __restrict__ es,
    const float* __restrict__ ew, int* __restrict__ bucket_cursor,
    uint2* __restrict__ binned)
{
    __shared__ uint2 stage[BIN_TILE];        // 32 KB
    __shared__ int h[NBUCK];                 // hist, then running cursor
    __shared__ int o[NBUCK];                 // exclusive offsets
    __shared__ int gbase[NBUCK];
    __shared__ int scanbuf[256];

    const int t = threadIdx.x;
    const int base = blockIdx.x * BIN_TILE;
    const int cnt = min(BIN_TILE, N_EDGES_C - base);

    for (int i = t; i < NBUCK; i += 256) h[i] = 0;
    __syncthreads();

    int ld[16]; int ls[16]; float lw[16]; int lb[16];
    #pragma unroll
    for (int k = 0; k < 16; ++k) {
        int i = t + k * 256;
        if (i < cnt) {
            int d = ed[base + i];
            ld[k] = d;
            ls[k] = es[base + i];
            lw[k] = ew[base + i];
            int b = d >> 10;
            lb[k] = b;
            atomicAdd(&h[b], 1);
        } else lb[k] = -1;
    }
    __syncthreads();

    // exclusive scan of h -> o (NBUCK <= 256)
    {
        int v = (t < NBUCK) ? h[t] : 0;
        scanbuf[t] = v;
        __syncthreads();
        for (int off = 1; off < 256; off <<= 1) {
            int x = (t >= off) ? scanbuf[t - off] : 0;
            __syncthreads();
            scanbuf[t] += x;
            __syncthreads();
        }
        if (t < NBUCK) o[t] = scanbuf[t] - v;
    }
    __syncthreads();

    if (t < NBUCK) h[t] = o[t];   // running cursors
    __syncthreads();

    #pragma unroll
    for (int k = 0; k < 16; ++k) {
        if (lb[k] >= 0) {
            int p = atomicAdd(&h[lb[k]], 1);
            unsigned key = ((unsigned)ls[k] << 10) | (unsigned)(ld[k] & 1023);
            stage[p] = make_uint2(key, __float_as_uint(lw[k]));
        }
    }
    __syncthreads();

    // reserve contiguous global space per bucket (h now = end offsets)
    if (t < NBUCK) {
        int c = h[t] - o[t];
        gbase[t] = (c > 0) ? atomicAdd(&bucket_cursor[t], c) : 0;
    }
    __syncthreads();

    // copy out, coalesced within bucket segments
    for (int i = t; i < cnt; i += 256) {
        int lo = 0, hi = NBUCK - 1;          // largest b with o[b] <= i
        while (lo < hi) {
            int mid = (lo + hi + 1) >> 1;
            if (o[mid] <= i) lo = mid; else hi = mid - 1;
        }
        binned[gbase[lo] + (i - o[lo])] = stage[i];
    }
}

// Pass B: one block owns one 1024-node bucket.  Builds the per-node
// histogram + scan from its own binned segment (emitting cursor[] as a
// by-product), then scatters to final CSR slots.  All adj writes land in
// one ~261KB region owned by this block -> L2 write combining.
__global__ __launch_bounds__(1024) void scatter_k(
    const uint2* __restrict__ binned, const int* __restrict__ bucket_base,
    int* __restrict__ cursor, uint2* __restrict__ adj)
{
    __shared__ int lh[1024];     // hist -> running cursor
    __shared__ int sdata[1024];  // scan workspace
    const int b = blockIdx.x;
    const int t = threadIdx.x;
    const int nb = b << 10;
    const int s0 = bucket_base[b];
    const int s1 = bucket_base[b + 1];

    lh[t] = 0;
    __syncthreads();
    for (int i = s0 + t; i < s1; i += 1024)
        atomicAdd(&lh[binned[i].x & 1023u], 1);
    __syncthreads();

    // exclusive scan of lh over 1024
    int v = lh[t];
    sdata[t] = v;
    __syncthreads();
    for (int off = 1; off < 1024; off <<= 1) {
        int x = (t >= off) ? sdata[t - off] : 0;
        __syncthreads();
        sdata[t] += x;
        __syncthreads();
    }
    const int start = s0 + sdata[t] - v;   // global CSR start for node nb+t
    if (nb + t < N_NODES) cursor[nb + t] = start;
    lh[t] = start;                          // running cursor
    __syncthreads();

    for (int i = s0 + t; i < s1; i += 1024) {
        uint2 e = binned[i];
        int ln = (int)(e.x & 1023u);
        int p = atomicAdd(&lh[ln], 1);
        adj[p] = make_uint2(e.x >> 10, e.y);
    }
}

// ---------------------------------------------------------------------------
// K3: fused aggregate + layernorm + residual (bf16 emb state)
// 4 edge-slot groups of 16 lanes; lane covers 4 cols (ushort4 per gather).
// ---------------------------------------------------------------------------
__global__ __launch_bounds__(256) void agg_ln_k(
    const unsigned short* __restrict__ emb_in,
    unsigned short* __restrict__ emb_out,
    float* __restrict__ acc_items,
    const int* __restrict__ cursor, const uint2* __restrict__ adj)
{
    const int n = blockIdx.x * 4 + (threadIdx.x >> 6);   // 37500 blocks exact
    const int lane = threadIdx.x & 63;
    const int g = lane >> 4;          // edge-slot group 0..3
    const int q = lane & 15;          // column quad: cols 4q..4q+3
    const int qo = q << 2;

    const int beg = cursor[n];
    const int end = (n == N_NODES - 1) ? N_EDGES_C : cursor[n + 1];

    float a0 = 0.f, a1 = 0.f, a2 = 0.f, a3 = 0.f;

    int j = beg;
    // main: 16 edges per iteration (4 chunks of 4)
    for (; j + 15 < end; j += 16) {
        uint2 e0 = adj[j + g];
        uint2 e1 = adj[j + 4 + g];
        uint2 e2 = adj[j + 8 + g];
        uint2 e3 = adj[j + 12 + g];
        ushort4 r0 = *reinterpret_cast<const ushort4*>(emb_in + (size_t)e0.x * DD + qo);
        ushort4 r1 = *reinterpret_cast<const ushort4*>(emb_in + (size_t)e1.x * DD + qo);
        ushort4 r2 = *reinterpret_cast<const ushort4*>(emb_in + (size_t)e2.x * DD + qo);
        ushort4 r3 = *reinterpret_cast<const ushort4*>(emb_in + (size_t)e3.x * DD + qo);
        float w0 = __uint_as_float(e0.y), w1 = __uint_as_float(e1.y);
        float w2 = __uint_as_float(e2.y), w3 = __uint_as_float(e3.y);
        a0 += w0 * b2f(r0.x); a1 += w0 * b2f(r0.y); a2 += w0 * b2f(r0.z); a3 += w0 * b2f(r0.w);
        a0 += w1 * b2f(r1.x); a1 += w1 * b2f(r1.y); a2 += w1 * b2f(r1.z); a3 += w1 * b2f(r1.w);
        a0 += w2 * b2f(r2.x); a1 += w2 * b2f(r2.y); a2 += w2 * b2f(r2.z); a3 += w2 * b2f(r2.w);
        a0 += w3 * b2f(r3.x); a1 += w3 * b2f(r3.y); a2 += w3 * b2f(r3.z); a3 += w3 * b2f(r3.w);
    }
    // 4-edge chunks
    for (; j + 3 < end; j += 4) {
        uint2 e = adj[j + g];
        ushort4 r = *reinterpret_cast<const ushort4*>(emb_in + (size_t)e.x * DD + qo);
        float w = __uint_as_float(e.y);
        a0 += w * b2f(r.x); a1 += w * b2f(r.y); a2 += w * b2f(r.z); a3 += w * b2f(r.w);
    }
    // tail (<4 edges): group g handles edge j+g if in range
    if (g < end - j) {
        uint2 e = adj[j + g];
        ushort4 r = *reinterpret_cast<const ushort4*>(emb_in + (size_t)e.x * DD + qo);
        float w = __uint_as_float(e.y);
        a0 += w * b2f(r.x); a1 += w * b2f(r.y); a2 += w * b2f(r.z); a3 += w * b2f(r.w);
    }

    // cross-group reduce: lanes {l, l^16, l^32, l^48} hold disjoint edge subsets
    a0 += __shfl_xor(a0, 16); a0 += __shfl_xor(a0, 32);
    a1 += __shfl_xor(a1, 16); a1 += __shfl_xor(a1, 32);
    a2 += __shfl_xor(a2, 16); a2 += __shfl_xor(a2, 32);
    a3 += __shfl_xor(a3, 16); a3 += __shfl_xor(a3, 32);

    // LN reductions over the 16 column-quads (replicated across groups)
    float s = a0 + a1 + a2 + a3;
    s += __shfl_xor(s, 1); s += __shfl_xor(s, 2);
    s += __shfl_xor(s, 4); s += __shfl_xor(s, 8);
    const float m = s * (1.f / 64.f);
    const float d0 = a0 - m, d1 = a1 - m, d2 = a2 - m, d3 = a3 - m;
    float vv = d0 * d0 + d1 * d1 + d2 * d2 + d3 * d3;
    vv += __shfl_xor(vv, 1); vv += __shfl_xor(vv, 2);
    vv += __shfl_xor(vv, 4); vv += __shfl_xor(vv, 8);
    const float rstd = rsqrtf(vv * (1.f / 64.f) + LN_EPS);

    // residual + write (group 0 only: avoids 4x duplicate stores)
    if (g == 0) {
        const size_t o = (size_t)n * DD + qo;
        ushort4 own = *reinterpret_cast<const ushort4*>(emb_in + o);
        float e0 = d0 * rstd + b2f(own.x);
        float e1 = d1 * rstd + b2f(own.y);
        float e2 = d2 * rstd + b2f(own.z);
        float e3 = d3 * rstd + b2f(own.w);
        ushort4 ob;
        ob.x = f2b(e0); ob.y = f2b(e1); ob.z = f2b(e2); ob.w = f2b(e3);
        *reinterpret_cast<ushort4*>(emb_out + o) = ob;
        if (n >= N_USERS) {
            float4* ap = reinterpret_cast<float4*>(
                acc_items + (size_t)(n - N_USERS) * DD + qo);
            float4 v = *ap;
            v.x += e0; v.y += e1; v.z += e2; v.w += e3;
            *ap = v;
        }
    }
}

// ---------------------------------------------------------------------------
// K4: accumulate sampled rows directly into out
// ---------------------------------------------------------------------------
__global__ __launch_bounds__(256) void gather_acc_k(
    const int* __restrict__ users, const int* __restrict__ pos,
    const int* __restrict__ neg, const unsigned short* __restrict__ emb_state,
    float* __restrict__ out, int init)
{
    int gid = blockIdx.x * 256 + threadIdx.x;   // 3*BATCH*DD = 786432
    int part = gid / (BATCH * DD);
    int r = gid - part * (BATCH * DD);
    int b = r >> 6, c = r & 63;
    int node;
    if (part == 0)      node = users[b];
    else if (part == 1) node = N_USERS + pos[b];
    else                node = N_USERS + neg[b];
    float v = b2f(emb_state[(size_t)node * DD + c]);
    if (init) out[gid] = v;
    else      out[gid] += v;
}

// ---------------------------------------------------------------------------
// K5: content loss
// ---------------------------------------------------------------------------
__global__ __launch_bounds__(256) void loss_k(
    const float* __restrict__ acc_items, const float* __restrict__ ic,
    float* __restrict__ loss_slot)
{
    const int total = N_ITEMS * DD;
    int stride = gridDim.x * 256;
    float p = 0.f;
    for (int i = blockIdx.x * 256 + threadIdx.x; i < total; i += stride) {
        float d = acc_items[i] * 0.25f - ic[i];
        p += d * d;
    }
    #pragma unroll
    for (int off = 32; off; off >>= 1) p += __shfl_xor(p, off);
    __shared__ float red[4];
    if ((threadIdx.x & 63) == 0) red[threadIdx.x >> 6] = p;
    __syncthreads();
    if (threadIdx.x == 0)
        atomicAdd(loss_slot, red[0] + red[1] + red[2] + red[3]);
}

// ---------------------------------------------------------------------------
// K6: out *= 0.25 ; write loss element
// ---------------------------------------------------------------------------
__global__ __launch_bounds__(256) void final_out_k(
    const float* __restrict__ loss_slot, float* __restrict__ out)
{
    int gid = blockIdx.x * 256 + threadIdx.x;
    out[gid] *= 0.25f;
    if (gid == 0)
        out[3 * BATCH * DD] =
            loss_slot[0] * (CONTENT_LOSS_W / (float)(N_ITEMS * DD));
}

// ---------------------------------------------------------------------------
extern "C" void kernel_launch(void* const* d_in, const int* in_sizes, int n_in,
                              void* d_out, int out_size, void* d_ws, size_t ws_size,
                              hipStream_t stream)
{
    const int* users = (const int*)d_in[0];
    const int* pos   = (const int*)d_in[1];
    const int* neg   = (const int*)d_in[2];
    const int* es    = (const int*)d_in[3];
    const int* ed    = (const int*)d_in[4];
    const float* ew  = (const float*)d_in[5];
    const float* ue  = (const float*)d_in[6];
    const float* ie  = (const float*)d_in[7];
    const float* cf  = (const float*)d_in[8];
    const float* Wp  = (const float*)d_in[9];
    const float* bp  = (const float*)d_in[10];
    const float* wg  = (const float*)d_in[11];
    const float* bg  = (const float*)d_in[12];
    float* out = (float*)d_out;

    // ---- workspace layout (~103 MB) ----
    unsigned short* embA = (unsigned short*)d_ws;             // 19.2 MB
    unsigned short* embB = embA + (size_t)N_NODES * DD;       // 19.2 MB
    float* acc_items = (float*)(embB + (size_t)N_NODES * DD); // 12.8 MB
    float* ic        = acc_items + (size_t)N_ITEMS * DD;      // 12.8 MB
    float* loss_slot = ic + (size_t)N_ITEMS * DD;             // 64 B
    int*   cursor    = (int*)(loss_slot + 16);                // 600 KB
    int*   bucket_cnt    = cursor + 150016;                   // 1 KB
    int*   bucket_base   = bucket_cnt + 256;                  // 1 KB
    int*   bucket_cursor = bucket_base + 256;                 // 1 KB
    uint2* adj       = (uint2*)(bucket_cursor + 256);         // 38.4 MB
    // binned scratch overlaps embB..ic (dead after scatter_k; CSR build
    // runs BEFORE content path / embB use). 38.4 MB <= 44.8 MB region.
    uint2* binned    = (uint2*)embB;
    // bstg (96 KB) parked in embA's USER region: content_mfma_k reads it
    // while writing only the ITEM region of embA; init_users_k overwrites
    // it afterwards (bstg dead by then). Zero workspace growth.
    unsigned short* bstg = embA;

    hipMemsetAsync(bucket_cnt, 0, 256 * sizeof(int), stream);
    hipMemsetAsync(loss_slot, 0, sizeof(float), stream);

    // ---- CSR build (no fine-grained global atomics anywhere) ----
    bucket_hist_k<<<HIST_BLKS, 256, 0, stream>>>(ed, bucket_cnt);
    bucket_scan_k<<<1, 256, 0, stream>>>(bucket_cnt, bucket_base, bucket_cursor);
    bin_k<<<(N_EDGES_C + BIN_TILE - 1) / BIN_TILE, 256, 0, stream>>>(
        ed, es, ew, bucket_cursor, binned);
    scatter_k<<<NBUCK, 1024, 0, stream>>>(binned, bucket_base, cursor, adj);

    // ---- content path (MFMA), then user init overwrites bstg ----
    wp_stage_k<<<192, 256, 0, stream>>>(Wp, bstg);
    content_mfma_k<<<(N_ITEMS / 16 + 3) / 4, 256, 0, stream>>>(
        cf, bstg, bp, wg, bg, ie, ic, embA, acc_items);
    init_users_k<<<(N_USERS * DD / 4) / 256, 256, 0, stream>>>(ue, embA);
    gather_acc_k<<<3 * BATCH * DD / 256, 256, 0, stream>>>(users, pos, neg,
                                                           embA, out, 1);

    // 3 propagation layers, ping-pong
    unsigned short* cur = embA;
    unsigned short* nxt = embB;
    for (int l = 0; l < 3; ++l) {
        agg_ln_k<<<N_NODES / 4, 256, 0, stream>>>(cur, nxt, acc_items,
                                                  cursor, adj);
        gather_acc_k<<<3 * BATCH * DD / 256, 256, 0, stream>>>(users, pos, neg,
                                                               nxt, out, 0);
        unsigned short* t = cur; cur = nxt; nxt = t;
    }

    loss_k<<<2048, 256, 0, stream>>>(acc_items, ic, loss_slot);
    final_out_k<<<3 * BATCH * DD / 256, 256, 0, stream>>>(loss_slot, out);
}

// Round 5
// 833.863 us; speedup vs baseline: 2.0655x; 1.0059x over previous
//
#include <hip/hip_runtime.h>
#include <hip/hip_bf16.h>

#define N_USERS 100000
#define N_ITEMS 50000
#define N_NODES 150000
#define DD 64
#define FF 768
#define N_EDGES_C 4800000
#define BATCH 4096
#define LN_EPS 1e-5f
#define CONTENT_LOSS_W 0.1f

#define NBUCK 147       // ceil(150000/1024) - 1024-node buckets
#define BIN_TILE 4096
#define HIST_BLKS 1200

#define KWIN 24         // 768 / 32 K-windows

typedef __attribute__((ext_vector_type(8))) short short8;
typedef __attribute__((ext_vector_type(4))) float f32x4;

__device__ inline float b2f(unsigned short v) {
    union { unsigned int i; float f; } u;
    u.i = ((unsigned int)v) << 16;
    return u.f;
}
__device__ inline unsigned short f2b(float f) {
    union { float f; unsigned int i; } u; u.f = f;
    unsigned int r = u.i + 0x7fff + ((u.i >> 16) & 1);   // RNE
    return (unsigned short)(r >> 16);
}
__device__ inline short bfc(float f) {
    __hip_bfloat16 h = __float2bfloat16(f);   // compiler emits v_cvt_pk_bf16_f32
    return *reinterpret_cast<short*>(&h);
}

// ---------------------------------------------------------------------------
// K1: user emb init f32 -> bf16
// ---------------------------------------------------------------------------
__global__ __launch_bounds__(256) void init_users_k(
    const float* __restrict__ ue, unsigned short* __restrict__ emb)
{
    int gid = blockIdx.x * 256 + threadIdx.x;   // N_USERS*DD/4 threads
    size_t base = (size_t)gid * 4;
    float4 v = *reinterpret_cast<const float4*>(ue + base);
    ushort4 o;
    o.x = f2b(v.x); o.y = f2b(v.y); o.z = f2b(v.z); o.w = f2b(v.w);
    *reinterpret_cast<ushort4*>(emb + base) = o;
}

// ---------------------------------------------------------------------------
// Wp (f32 [768][64]) -> bf16 B-fragment-staged layout for mfma 16x16x32.
// bstg index: (((kw*4)+nt)*64 + lane)*8 + e
//   holds Wp[kw*32 + (lane>>4)*8 + e][nt*16 + (lane&15)]
// ---------------------------------------------------------------------------
__global__ __launch_bounds__(256) void wp_stage_k(
    const float* __restrict__ Wp, unsigned short* __restrict__ bstg)
{
    int tid = blockIdx.x * 256 + threadIdx.x;   // 49152 threads
    int e    = tid & 7;
    int lane = (tid >> 3) & 63;
    int nt   = (tid >> 9) & 3;
    int kw   = tid >> 11;
    int k = kw * 32 + ((lane >> 4) << 3) + e;
    int n = nt * 16 + (lane & 15);
    bstg[tid] = (unsigned short)bfc(Wp[k * DD + n]);
}

// ---------------------------------------------------------------------------
// K2: content projection (bf16 MFMA) + f32 gate + combine.  Zero LDS.
// ---------------------------------------------------------------------------
__global__ __launch_bounds__(256) void content_mfma_k(
    const float* __restrict__ cf, const unsigned short* __restrict__ bstg,
    const float* __restrict__ bp, const float* __restrict__ wg,
    const float* __restrict__ bg, const float* __restrict__ item_emb,
    float* __restrict__ items_content,
    unsigned short* __restrict__ emb, float* __restrict__ acc_items)
{
    const int wt = blockIdx.x * 4 + (threadIdx.x >> 6);
    if (wt >= N_ITEMS / 16) return;
    const int lane = threadIdx.x & 63;
    const int row0 = wt * 16;

    const int lrow = lane & 15;          // row within tile (A operand)
    const int kgrp = lane >> 4;          // k-chunk 0..3

    const float* aptr = cf + (size_t)(row0 + lrow) * FF + (kgrp << 3);
    const float* wptr = wg + (kgrp << 3);
    const short8* bptr = reinterpret_cast<const short8*>(bstg) + lane;

    f32x4 acc0 = {0.f, 0.f, 0.f, 0.f};
    f32x4 acc1 = {0.f, 0.f, 0.f, 0.f};
    f32x4 acc2 = {0.f, 0.f, 0.f, 0.f};
    f32x4 acc3 = {0.f, 0.f, 0.f, 0.f};
    float gp = 0.f;

    #pragma unroll 4
    for (int kw = 0; kw < KWIN; ++kw) {
        float4 a0 = *reinterpret_cast<const float4*>(aptr + kw * 32);
        float4 a1 = *reinterpret_cast<const float4*>(aptr + kw * 32 + 4);
        float4 w0 = *reinterpret_cast<const float4*>(wptr + kw * 32);
        float4 w1 = *reinterpret_cast<const float4*>(wptr + kw * 32 + 4);

        gp += a0.x * w0.x + a0.y * w0.y + a0.z * w0.z + a0.w * w0.w;
        gp += a1.x * w1.x + a1.y * w1.y + a1.z * w1.z + a1.w * w1.w;

        short8 af;
        af[0] = bfc(a0.x); af[1] = bfc(a0.y); af[2] = bfc(a0.z); af[3] = bfc(a0.w);
        af[4] = bfc(a1.x); af[5] = bfc(a1.y); af[6] = bfc(a1.z); af[7] = bfc(a1.w);

        const short8* bb = bptr + (size_t)kw * 256;   // (kw*4+nt)*64+lane
        short8 b0 = bb[0];
        short8 b1 = bb[64];
        short8 b2 = bb[128];
        short8 b3 = bb[192];

        acc0 = __builtin_amdgcn_mfma_f32_16x16x32_bf16(af, b0, acc0, 0, 0, 0);
        acc1 = __builtin_amdgcn_mfma_f32_16x16x32_bf16(af, b1, acc1, 0, 0, 0);
        acc2 = __builtin_amdgcn_mfma_f32_16x16x32_bf16(af, b2, acc2, 0, 0, 0);
        acc3 = __builtin_amdgcn_mfma_f32_16x16x32_bf16(af, b3, acc3, 0, 0, 0);
    }

    // gate: lanes {l, l^16, l^32, l^48} hold k-partials for row lane&15
    gp += __shfl_xor(gp, 16);
    gp += __shfl_xor(gp, 32);
    const float g = 1.f / (1.f + __expf(-(gp + bg[0])));

    // epilogue: C layout col=lane&15, row=(lane>>4)*4+reg
    const int rbase = kgrp << 2;
    f32x4 accs[4] = {acc0, acc1, acc2, acc3};
    #pragma unroll
    for (int nt = 0; nt < 4; ++nt) {
        const int col = nt * 16 + lrow;
        const float bpv = bp[col];
        #pragma unroll
        for (int r = 0; r < 4; ++r) {
            const int rit = rbase + r;
            const int row = row0 + rit;
            const float ic = accs[nt][r] + bpv;
            const float gr = __shfl(g, rit);
            const size_t o = (size_t)row * DD + col;
            const float it = (1.f - gr) * item_emb[o] + gr * ic;
            items_content[o] = ic;
            emb[(size_t)(N_USERS + row) * DD + col] = f2b(it);
            acc_items[o] = it;
        }
    }
}

// ---------------------------------------------------------------------------
// CSR build v3: coarse bucket hist (LDS-privatized, no fine global atomics)
//   -> 147-scan -> bin (write-combined) -> per-bucket scatter that derives
//   per-node cursors in LDS and emits the global cursor array.
// ---------------------------------------------------------------------------
__global__ __launch_bounds__(256) void bucket_hist_k(
    const int* __restrict__ ed, int* __restrict__ bucket_cnt)
{
    __shared__ int lh[NBUCK];
    for (int i = threadIdx.x; i < NBUCK; i += 256) lh[i] = 0;
    __syncthreads();
    const int stride = HIST_BLKS * 256;
    for (int t = blockIdx.x * 256 + threadIdx.x; t < N_EDGES_C / 4; t += stride) {
        int4 d = reinterpret_cast<const int4*>(ed)[t];
        atomicAdd(&lh[d.x >> 10], 1);
        atomicAdd(&lh[d.y >> 10], 1);
        atomicAdd(&lh[d.z >> 10], 1);
        atomicAdd(&lh[d.w >> 10], 1);
    }
    __syncthreads();
    for (int i = threadIdx.x; i < NBUCK; i += 256) {
        int c = lh[i];
        if (c) atomicAdd(&bucket_cnt[i], c);
    }
}

// single block: exclusive scan of 147 bucket counts -> bucket_base[148],
// and init bucket_cursor = base.
__global__ __launch_bounds__(256) void bucket_scan_k(
    const int* __restrict__ bucket_cnt, int* __restrict__ bucket_base,
    int* __restrict__ bucket_cursor)
{
    __shared__ int sdata[256];
    int t = threadIdx.x;
    int v = (t < NBUCK) ? bucket_cnt[t] : 0;
    sdata[t] = v;
    __syncthreads();
    for (int off = 1; off < 256; off <<= 1) {
        int x = (t >= off) ? sdata[t - off] : 0;
        __syncthreads();
        sdata[t] += x;
        __syncthreads();
    }
    if (t < NBUCK) {
        int b = sdata[t] - v;   // exclusive
        bucket_base[t] = b;
        bucket_cursor[t] = b;
    }
    if (t == NBUCK - 1) bucket_base[NBUCK] = sdata[t];   // == N_EDGES_C
}

// Pass A: tile-sort edges into 147 coarse buckets with LDS write combining.
// binned entry: x = (src<<10)|(dst&1023), y = weight bits
__global__ __launch_bounds__(256) void bin_k(
    const int* __restrict__ ed, const int* __restrict__ es,
    const float* __restrict__ ew, int* __restrict__ bucket_cursor,
    uint2* __restrict__ binned)
{
    __shared__ uint2 stage[BIN_TILE];        // 32 KB
    __shared__ int h[NBUCK];                 // hist, then running cursor
    __shared__ int o[NBUCK];                 // exclusive offsets
    __shared__ int gbase[NBUCK];
    __shared__ int scanbuf[256];

    const int t = threadIdx.x;
    const int base = blockIdx.x * BIN_TILE;
    const int cnt = min(BIN_TILE, N_EDGES_C - base);

    for (int i = t; i < NBUCK; i += 256) h[i] = 0;
    __syncthreads();

    int ld[16]; int ls[16]; float lw[16]; int lb[16];
    #pragma unroll
    for (int k = 0; k < 16; ++k) {
        int i = t + k * 256;
        if (i < cnt) {
            int d = ed[base + i];
            ld[k] = d;
            ls[k] = es[base + i];
            lw[k] = ew[base + i];
            int b = d >> 10;
            lb[k] = b;
            atomicAdd(&h[b], 1);
        } else lb[k] = -1;
    }
    __syncthreads();

    // exclusive scan of h -> o (NBUCK <= 256)
    {
        int v = (t < NBUCK) ? h[t] : 0;
        scanbuf[t] = v;
        __syncthreads();
        for (int off = 1; off < 256; off <<= 1) {
            int x = (t >= off) ? scanbuf[t - off] : 0;
            __syncthreads();
            scanbuf[t] += x;
            __syncthreads();
        }
        if (t < NBUCK) o[t] = scanbuf[t] - v;
    }
    __syncthreads();

    if (t < NBUCK) h[t] = o[t];   // running cursors
    __syncthreads();

    #pragma unroll
    for (int k = 0; k < 16; ++k) {
        if (lb[k] >= 0) {
            int p = atomicAdd(&h[lb[k]], 1);
            unsigned key = ((unsigned)ls[k] << 10) | (unsigned)(ld[k] & 1023);
            stage[p] = make_uint2(key, __float_as_uint(lw[k]));
        }
    }
    __syncthreads();

    // reserve contiguous global space per bucket (h now = end offsets)
    if (t < NBUCK) {
        int c = h[t] - o[t];
        gbase[t] = (c > 0) ? atomicAdd(&bucket_cursor[t], c) : 0;
    }
    __syncthreads();

    // copy out, coalesced within bucket segments
    for (int i = t; i < cnt; i += 256) {
        int lo = 0, hi = NBUCK - 1;          // largest b with o[b] <= i
        while (lo < hi) {
            int mid = (lo + hi + 1) >> 1;
            if (o[mid] <= i) lo = mid; else hi = mid - 1;
        }
        binned[gbase[lo] + (i - o[lo])] = stage[i];
    }
}

// Pass B: one block owns one 1024-node bucket.  Builds the per-node
// histogram + scan from its own binned segment (emitting cursor[] as a
// by-product), then scatters to final CSR slots.
__global__ __launch_bounds__(1024) void scatter_k(
    const uint2* __restrict__ binned, const int* __restrict__ bucket_base,
    int* __restrict__ cursor, uint2* __restrict__ adj)
{
    __shared__ int lh[1024];     // hist -> running cursor
    __shared__ int sdata[1024];  // scan workspace
    const int b = blockIdx.x;
    const int t = threadIdx.x;
    const int nb = b << 10;
    const int s0 = bucket_base[b];
    const int s1 = bucket_base[b + 1];

    lh[t] = 0;
    __syncthreads();
    for (int i = s0 + t; i < s1; i += 1024)
        atomicAdd(&lh[binned[i].x & 1023u], 1);
    __syncthreads();

    // exclusive scan of lh over 1024
    int v = lh[t];
    sdata[t] = v;
    __syncthreads();
    for (int off = 1; off < 1024; off <<= 1) {
        int x = (t >= off) ? sdata[t - off] : 0;
        __syncthreads();
        sdata[t] += x;
        __syncthreads();
    }
    const int start = s0 + sdata[t] - v;   // global CSR start for node nb+t
    if (nb + t < N_NODES) cursor[nb + t] = start;
    lh[t] = start;                          // running cursor
    __syncthreads();

    for (int i = s0 + t; i < s1; i += 1024) {
        uint2 e = binned[i];
        int ln = (int)(e.x & 1023u);
        int p = atomicAdd(&lh[ln], 1);
        adj[p] = make_uint2(e.x >> 10, e.y);
    }
}

// ---------------------------------------------------------------------------
// K3: fused aggregate + layernorm + residual (bf16 emb state)
// 4 edge-slot groups of 16 lanes; lane covers 4 cols (ushort4 per gather).
// Main loop: 32 edges/iter -> 8 independent row-gathers in flight per lane.
// ---------------------------------------------------------------------------
__global__ __launch_bounds__(256) void agg_ln_k(
    const unsigned short* __restrict__ emb_in,
    unsigned short* __restrict__ emb_out,
    float* __restrict__ acc_items,
    const int* __restrict__ cursor, const uint2* __restrict__ adj)
{
    const int n = blockIdx.x * 4 + (threadIdx.x >> 6);   // 37500 blocks exact
    const int lane = threadIdx.x & 63;
    const int g = lane >> 4;          // edge-slot group 0..3
    const int q = lane & 15;          // column quad: cols 4q..4q+3
    const int qo = q << 2;

    const int beg = cursor[n];
    const int end = (n == N_NODES - 1) ? N_EDGES_C : cursor[n + 1];

    float a0 = 0.f, a1 = 0.f, a2 = 0.f, a3 = 0.f;

    int j = beg;
    // main: 32 edges per iteration (8 chunks of 4) - deep MLP
    for (; j + 31 < end; j += 32) {
        uint2 e0 = adj[j      + g];
        uint2 e1 = adj[j +  4 + g];
        uint2 e2 = adj[j +  8 + g];
        uint2 e3 = adj[j + 12 + g];
        uint2 e4 = adj[j + 16 + g];
        uint2 e5 = adj[j + 20 + g];
        uint2 e6 = adj[j + 24 + g];
        uint2 e7 = adj[j + 28 + g];
        ushort4 r0 = *reinterpret_cast<const ushort4*>(emb_in + (size_t)e0.x * DD + qo);
        ushort4 r1 = *reinterpret_cast<const ushort4*>(emb_in + (size_t)e1.x * DD + qo);
        ushort4 r2 = *reinterpret_cast<const ushort4*>(emb_in + (size_t)e2.x * DD + qo);
        ushort4 r3 = *reinterpret_cast<const ushort4*>(emb_in + (size_t)e3.x * DD + qo);
        ushort4 r4 = *reinterpret_cast<const ushort4*>(emb_in + (size_t)e4.x * DD + qo);
        ushort4 r5 = *reinterpret_cast<const ushort4*>(emb_in + (size_t)e5.x * DD + qo);
        ushort4 r6 = *reinterpret_cast<const ushort4*>(emb_in + (size_t)e6.x * DD + qo);
        ushort4 r7 = *reinterpret_cast<const ushort4*>(emb_in + (size_t)e7.x * DD + qo);
        float w0 = __uint_as_float(e0.y), w1 = __uint_as_float(e1.y);
        float w2 = __uint_as_float(e2.y), w3 = __uint_as_float(e3.y);
        float w4 = __uint_as_float(e4.y), w5 = __uint_as_float(e5.y);
        float w6 = __uint_as_float(e6.y), w7 = __uint_as_float(e7.y);
        a0 += w0 * b2f(r0.x); a1 += w0 * b2f(r0.y); a2 += w0 * b2f(r0.z); a3 += w0 * b2f(r0.w);
        a0 += w1 * b2f(r1.x); a1 += w1 * b2f(r1.y); a2 += w1 * b2f(r1.z); a3 += w1 * b2f(r1.w);
        a0 += w2 * b2f(r2.x); a1 += w2 * b2f(r2.y); a2 += w2 * b2f(r2.z); a3 += w2 * b2f(r2.w);
        a0 += w3 * b2f(r3.x); a1 += w3 * b2f(r3.y); a2 += w3 * b2f(r3.z); a3 += w3 * b2f(r3.w);
        a0 += w4 * b2f(r4.x); a1 += w4 * b2f(r4.y); a2 += w4 * b2f(r4.z); a3 += w4 * b2f(r4.w);
        a0 += w5 * b2f(r5.x); a1 += w5 * b2f(r5.y); a2 += w5 * b2f(r5.z); a3 += w5 * b2f(r5.w);
        a0 += w6 * b2f(r6.x); a1 += w6 * b2f(r6.y); a2 += w6 * b2f(r6.z); a3 += w6 * b2f(r6.w);
        a0 += w7 * b2f(r7.x); a1 += w7 * b2f(r7.y); a2 += w7 * b2f(r7.z); a3 += w7 * b2f(r7.w);
    }
    // 16-edge chunk
    if (j + 15 < end) {
        uint2 e0 = adj[j + g];
        uint2 e1 = adj[j + 4 + g];
        uint2 e2 = adj[j + 8 + g];
        uint2 e3 = adj[j + 12 + g];
        ushort4 r0 = *reinterpret_cast<const ushort4*>(emb_in + (size_t)e0.x * DD + qo);
        ushort4 r1 = *reinterpret_cast<const ushort4*>(emb_in + (size_t)e1.x * DD + qo);
        ushort4 r2 = *reinterpret_cast<const ushort4*>(emb_in + (size_t)e2.x * DD + qo);
        ushort4 r3 = *reinterpret_cast<const ushort4*>(emb_in + (size_t)e3.x * DD + qo);
        float w0 = __uint_as_float(e0.y), w1 = __uint_as_float(e1.y);
        float w2 = __uint_as_float(e2.y), w3 = __uint_as_float(e3.y);
        a0 += w0 * b2f(r0.x); a1 += w0 * b2f(r0.y); a2 += w0 * b2f(r0.z); a3 += w0 * b2f(r0.w);
        a0 += w1 * b2f(r1.x); a1 += w1 * b2f(r1.y); a2 += w1 * b2f(r1.z); a3 += w1 * b2f(r1.w);
        a0 += w2 * b2f(r2.x); a1 += w2 * b2f(r2.y); a2 += w2 * b2f(r2.z); a3 += w2 * b2f(r2.w);
        a0 += w3 * b2f(r3.x); a1 += w3 * b2f(r3.y); a2 += w3 * b2f(r3.z); a3 += w3 * b2f(r3.w);
        j += 16;
    }
    // 4-edge chunks
    for (; j + 3 < end; j += 4) {
        uint2 e = adj[j + g];
        ushort4 r = *reinterpret_cast<const ushort4*>(emb_in + (size_t)e.x * DD + qo);
        float w = __uint_as_float(e.y);
        a0 += w * b2f(r.x); a1 += w * b2f(r.y); a2 += w * b2f(r.z); a3 += w * b2f(r.w);
    }
    // tail (<4 edges): group g handles edge j+g if in range
    if (g < end - j) {
        uint2 e = adj[j + g];
        ushort4 r = *reinterpret_cast<const ushort4*>(emb_in + (size_t)e.x * DD + qo);
        float w = __uint_as_float(e.y);
        a0 += w * b2f(r.x); a1 += w * b2f(r.y); a2 += w * b2f(r.z); a3 += w * b2f(r.w);
    }

    // cross-group reduce: lanes {l, l^16, l^32, l^48} hold disjoint edge subsets
    a0 += __shfl_xor(a0, 16); a0 += __shfl_xor(a0, 32);
    a1 += __shfl_xor(a1, 16); a1 += __shfl_xor(a1, 32);
    a2 += __shfl_xor(a2, 16); a2 += __shfl_xor(a2, 32);
    a3 += __shfl_xor(a3, 16); a3 += __shfl_xor(a3, 32);

    // LN reductions over the 16 column-quads (replicated across groups)
    float s = a0 + a1 + a2 + a3;
    s += __shfl_xor(s, 1); s += __shfl_xor(s, 2);
    s += __shfl_xor(s, 4); s += __shfl_xor(s, 8);
    const float m = s * (1.f / 64.f);
    const float d0 = a0 - m, d1 = a1 - m, d2 = a2 - m, d3 = a3 - m;
    float vv = d0 * d0 + d1 * d1 + d2 * d2 + d3 * d3;
    vv += __shfl_xor(vv, 1); vv += __shfl_xor(vv, 2);
    vv += __shfl_xor(vv, 4); vv += __shfl_xor(vv, 8);
    const float rstd = rsqrtf(vv * (1.f / 64.f) + LN_EPS);

    // residual + write (group 0 only: avoids 4x duplicate stores)
    if (g == 0) {
        const size_t o = (size_t)n * DD + qo;
        ushort4 own = *reinterpret_cast<const ushort4*>(emb_in + o);
        float e0 = d0 * rstd + b2f(own.x);
        float e1 = d1 * rstd + b2f(own.y);
        float e2 = d2 * rstd + b2f(own.z);
        float e3 = d3 * rstd + b2f(own.w);
        ushort4 ob;
        ob.x = f2b(e0); ob.y = f2b(e1); ob.z = f2b(e2); ob.w = f2b(e3);
        *reinterpret_cast<ushort4*>(emb_out + o) = ob;
        if (n >= N_USERS) {
            float4* ap = reinterpret_cast<float4*>(
                acc_items + (size_t)(n - N_USERS) * DD + qo);
            float4 v = *ap;
            v.x += e0; v.y += e1; v.z += e2; v.w += e3;
            *ap = v;
        }
    }
}

// ---------------------------------------------------------------------------
// K4: accumulate sampled rows directly into out
// ---------------------------------------------------------------------------
__global__ __launch_bounds__(256) void gather_acc_k(
    const int* __restrict__ users, const int* __restrict__ pos,
    const int* __restrict__ neg, const unsigned short* __restrict__ emb_state,
    float* __restrict__ out, int init)
{
    int gid = blockIdx.x * 256 + threadIdx.x;   // 3*BATCH*DD = 786432
    int part = gid / (BATCH * DD);
    int r = gid - part * (BATCH * DD);
    int b = r >> 6, c = r & 63;
    int node;
    if (part == 0)      node = users[b];
    else if (part == 1) node = N_USERS + pos[b];
    else                node = N_USERS + neg[b];
    float v = b2f(emb_state[(size_t)node * DD + c]);
    if (init) out[gid] = v;
    else      out[gid] += v;
}

// ---------------------------------------------------------------------------
// K5: content loss
// ---------------------------------------------------------------------------
__global__ __launch_bounds__(256) void loss_k(
    const float* __restrict__ acc_items, const float* __restrict__ ic,
    float* __restrict__ loss_slot)
{
    const int total = N_ITEMS * DD;
    int stride = gridDim.x * 256;
    float p = 0.f;
    for (int i = blockIdx.x * 256 + threadIdx.x; i < total; i += stride) {
        float d = acc_items[i] * 0.25f - ic[i];
        p += d * d;
    }
    #pragma unroll
    for (int off = 32; off; off >>= 1) p += __shfl_xor(p, off);
    __shared__ float red[4];
    if ((threadIdx.x & 63) == 0) red[threadIdx.x >> 6] = p;
    __syncthreads();
    if (threadIdx.x == 0)
        atomicAdd(loss_slot, red[0] + red[1] + red[2] + red[3]);
}

// ---------------------------------------------------------------------------
// K6: out *= 0.25 ; write loss element
// ---------------------------------------------------------------------------
__global__ __launch_bounds__(256) void final_out_k(
    const float* __restrict__ loss_slot, float* __restrict__ out)
{
    int gid = blockIdx.x * 256 + threadIdx.x;
    out[gid] *= 0.25f;
    if (gid == 0)
        out[3 * BATCH * DD] =
            loss_slot[0] * (CONTENT_LOSS_W / (float)(N_ITEMS * DD));
}

// ---------------------------------------------------------------------------
extern "C" void kernel_launch(void* const* d_in, const int* in_sizes, int n_in,
                              void* d_out, int out_size, void* d_ws, size_t ws_size,
                              hipStream_t stream)
{
    const int* users = (const int*)d_in[0];
    const int* pos   = (const int*)d_in[1];
    const int* neg   = (const int*)d_in[2];
    const int* es    = (const int*)d_in[3];
    const int* ed    = (const int*)d_in[4];
    const float* ew  = (const float*)d_in[5];
    const float* ue  = (const float*)d_in[6];
    const float* ie  = (const float*)d_in[7];
    const float* cf  = (const float*)d_in[8];
    const float* Wp  = (const float*)d_in[9];
    const float* bp  = (const float*)d_in[10];
    const float* wg  = (const float*)d_in[11];
    const float* bg  = (const float*)d_in[12];
    float* out = (float*)d_out;

    // ---- workspace layout (~103 MB) ----
    unsigned short* embA = (unsigned short*)d_ws;             // 19.2 MB
    unsigned short* embB = embA + (size_t)N_NODES * DD;       // 19.2 MB
    float* acc_items = (float*)(embB + (size_t)N_NODES * DD); // 12.8 MB
    float* ic        = acc_items + (size_t)N_ITEMS * DD;      // 12.8 MB
    float* loss_slot = ic + (size_t)N_ITEMS * DD;             // 64 B
    int*   cursor    = (int*)(loss_slot + 16);                // 600 KB
    int*   bucket_cnt    = cursor + 150016;                   // 1 KB
    int*   bucket_base   = bucket_cnt + 256;                  // 1 KB
    int*   bucket_cursor = bucket_base + 256;                 // 1 KB
    uint2* adj       = (uint2*)(bucket_cursor + 256);         // 38.4 MB
    // binned scratch overlaps embB..ic (dead after scatter_k; CSR build
    // runs BEFORE content path / embB use). 38.4 MB <= 44.8 MB region.
    uint2* binned    = (uint2*)embB;
    // bstg (96 KB) parked in embA's USER region: content_mfma_k reads it
    // while writing only the ITEM region of embA; init_users_k overwrites
    // it afterwards (bstg dead by then). Zero workspace growth.
    unsigned short* bstg = embA;

    hipMemsetAsync(bucket_cnt, 0, 256 * sizeof(int), stream);
    hipMemsetAsync(loss_slot, 0, sizeof(float), stream);

    // ---- CSR build (no fine-grained global atomics anywhere) ----
    bucket_hist_k<<<HIST_BLKS, 256, 0, stream>>>(ed, bucket_cnt);
    bucket_scan_k<<<1, 256, 0, stream>>>(bucket_cnt, bucket_base, bucket_cursor);
    bin_k<<<(N_EDGES_C + BIN_TILE - 1) / BIN_TILE, 256, 0, stream>>>(
        ed, es, ew, bucket_cursor, binned);
    scatter_k<<<NBUCK, 1024, 0, stream>>>(binned, bucket_base, cursor, adj);

    // ---- content path (MFMA), then user init overwrites bstg ----
    wp_stage_k<<<192, 256, 0, stream>>>(Wp, bstg);
    content_mfma_k<<<(N_ITEMS / 16 + 3) / 4, 256, 0, stream>>>(
        cf, bstg, bp, wg, bg, ie, ic, embA, acc_items);
    init_users_k<<<(N_USERS * DD / 4) / 256, 256, 0, stream>>>(ue, embA);
    gather_acc_k<<<3 * BATCH * DD / 256, 256, 0, stream>>>(users, pos, neg,
                                                           embA, out, 1);

    // 3 propagation layers, ping-pong
    unsigned short* cur = embA;
    unsigned short* nxt = embB;
    for (int l = 0; l < 3; ++l) {
        agg_ln_k<<<N_NODES / 4, 256, 0, stream>>>(cur, nxt, acc_items,
                                                  cursor, adj);
        gather_acc_k<<<3 * BATCH * DD / 256, 256, 0, stream>>>(users, pos, neg,
                                                               nxt, out, 0);
        unsigned short* t = cur; cur = nxt; nxt = t;
    }

    loss_k<<<2048, 256, 0, stream>>>(acc_items, ic, loss_slot);
    final_out_k<<<3 * BATCH * DD / 256, 256, 0, stream>>>(loss_slot, out);
}